// Round 4
// baseline (2912.518 us; speedup 1.0000x reference)
//
#include <hip/hip_runtime.h>
#include <hip/hip_bf16.h>
#include <math.h>

#define B_  64
#define A_  26
#define L_  384
#define D_  512
#define K_  18
#define LP1 385   // L_ + 1
#define VS  384   // Vsto row stride; Vsto[i-1][j-1] = V[i][j] (rows/cols 1..384 stored at 0..383)
#define CF  64    // forward chunk (columns per superstep)
#define CB  32    // backward chunk

// ---------------- conv weight transpose: (D,A,K) -> (A*K, D) ----------------
__global__ void transpose_w_kernel(const float* __restrict__ w, float* __restrict__ wt) {
    int o = blockIdx.x * blockDim.x + threadIdx.x;   // o = r*D + d
    int total = A_ * K_ * D_;
    if (o >= total) return;
    int d = o % D_;
    int r = o / D_;                                   // r = a*K + k
    wt[o] = w[(size_t)d * (A_ * K_) + r];
}

// ---------------- conv1d -> e (B, L, D) ----------------
__global__ __launch_bounds__(512) void conv_kernel(const float* __restrict__ x,     // (B, A, L)
                                                   const float* __restrict__ wt,    // (A*K, D)
                                                   const float* __restrict__ bias,  // (D,)
                                                   float* __restrict__ e) {         // (B, L, D)
    const int TL = 32;
    const int XW = TL + K_ - 1;     // 49
    int l0 = blockIdx.x * TL;
    int b  = blockIdx.y;
    int d  = threadIdx.x;           // 512 threads, one per output channel
    __shared__ float xs[A_][XW];
    for (int idx = threadIdx.x; idx < A_ * XW; idx += 512) {
        int a = idx / XW, p = idx % XW;
        int g = l0 - (K_ - 1) / 2 + p;  // l0 - 8 + p
        xs[a][p] = (g >= 0 && g < L_) ? x[((size_t)b * A_ + a) * L_ + g] : 0.0f;
    }
    __syncthreads();
    float acc[TL];
#pragma unroll
    for (int l = 0; l < TL; ++l) acc[l] = 0.0f;
#pragma unroll 1
    for (int a = 0; a < A_; ++a) {
        float xr[XW];
#pragma unroll
        for (int p = 0; p < XW; ++p) xr[p] = xs[a][p];
        const float* wrow = wt + (size_t)(a * K_) * D_ + d;
#pragma unroll
        for (int k = 0; k < K_; ++k) {
            float w = wrow[(size_t)k * D_];
#pragma unroll
            for (int l = 0; l < TL; ++l)
                acc[l] = fmaf(xr[k + l], w, acc[l]);
        }
    }
    float bv = bias[d];
#pragma unroll
    for (int l = 0; l < TL; ++l)
        e[((size_t)b * L_ + (l0 + l)) * D_ + d] = acc[l] + bv;
}

// ---------------- sim[b,l,m] = dot(e[b,l,:], e[0,m,:]) ----------------
__global__ __launch_bounds__(256) void sim_kernel(const float* __restrict__ e, float* __restrict__ sim) {
    int b  = blockIdx.z;
    int m0 = blockIdx.x * 32;
    int l0 = blockIdx.y * 32;
    __shared__ float As[32][33];
    __shared__ float Bs[32][33];
    int tid = threadIdx.x;
    int tx = tid & 15, ty = tid >> 4;
    const float* ea = e + (size_t)b * L_ * D_;
    const float* e0 = e;   // batch 0
    float acc00 = 0.f, acc01 = 0.f, acc10 = 0.f, acc11 = 0.f;
    int lrow = tid >> 3;          // 0..31
    int lcol = (tid & 7) << 2;    // 0,4,..,28
    for (int kc = 0; kc < D_; kc += 32) {
        float4 av = *(const float4*)(ea + (size_t)(l0 + lrow) * D_ + kc + lcol);
        float4 bv = *(const float4*)(e0 + (size_t)(m0 + lrow) * D_ + kc + lcol);
        As[lrow][lcol + 0] = av.x; As[lrow][lcol + 1] = av.y;
        As[lrow][lcol + 2] = av.z; As[lrow][lcol + 3] = av.w;
        Bs[lrow][lcol + 0] = bv.x; Bs[lrow][lcol + 1] = bv.y;
        Bs[lrow][lcol + 2] = bv.z; Bs[lrow][lcol + 3] = bv.w;
        __syncthreads();
#pragma unroll
        for (int kk = 0; kk < 32; ++kk) {
            float a0 = As[2 * ty][kk], a1 = As[2 * ty + 1][kk];
            float b0 = Bs[2 * tx][kk], b1 = Bs[2 * tx + 1][kk];
            acc00 = fmaf(a0, b0, acc00); acc01 = fmaf(a0, b1, acc01);
            acc10 = fmaf(a1, b0, acc10); acc11 = fmaf(a1, b1, acc11);
        }
        __syncthreads();
    }
    float* sp = sim + ((size_t)b * L_ + l0) * L_ + m0;
    sp[(2 * ty + 0) * L_ + 2 * tx + 0] = acc00;
    sp[(2 * ty + 0) * L_ + 2 * tx + 1] = acc01;
    sp[(2 * ty + 1) * L_ + 2 * tx + 0] = acc10;
    sp[(2 * ty + 1) * L_ + 2 * tx + 1] = acc11;
}

// ---------------- NW forward: wave-skewed pipeline, LDS tile dual-use ----------------
// V[i,j] = sim[i-1,j-1] + smoothmax3(V[i-1,j-1], V[i-1,j], V[i,j-1])   (g=0, t=1)
// Lane l of wave w owns row i = 64w+1+l. Tile[w][l][q] starts as sim[i-1, j0+q],
// gets overwritten in place by V[i, j0+1+q] (each slot read exactly once, at the
// step that produces that cell's V). Flush is coalesced float4 at chunk end.
// V stored compactly: Vsto[i-1][j-1] = V[i][j], per-batch stride L*L (16B aligned).
__global__ __launch_bounds__(384, 1) void nw_fwd_kernel(const float* __restrict__ sim, float* __restrict__ V) {
    int b = blockIdx.x;
    const float* sb = sim + (size_t)b * L_ * L_;
    float* Vb = V + (size_t)b * L_ * L_;             // Vsto layout
    __shared__ float tile[6][64][68];    // stride 68: 16B-aligned float4, 2-way-bank skewed reads
    __shared__ float bot[2][6][CF + 1];  // [parity][wave][0..CF], idx0 = carry V[64w+64, j0]
    int tid = threadIdx.x;
    int w = tid >> 6, l = tid & 63;
    float left = 0.0f;                       // V[i, 0] = 0 boundary
    const int nch = L_ / CF;                 // 6
    for (int T = 0; T < nch + 5; ++T) {
        int c = T - w;
        if (c >= 0 && c < nch) {
            int j0 = c * CF;
            // cooperative coalesced stage: sim rows 64w..64w+63, cols j0..j0+63
#pragma unroll
            for (int it = 0; it < 16; ++it) {
                int idx = (it << 6) + l;
                int r = idx >> 4, q4 = idx & 15;
                float4 v = *(const float4*)(sb + (size_t)((w << 6) + r) * L_ + j0 + (q4 << 2));
                *(float4*)&tile[w][r][q4 << 2] = v;
            }
            const float* botprev = bot[c & 1][(w == 0) ? 0 : (w - 1)];
            float* botcur = bot[c & 1][w];
            if (l == 63) botcur[0] = left;   // carry V[64w+64, j0]
            float cur = left;
            float prev_nb = (l == 0) ? ((w == 0) ? 0.f : botprev[0]) : 0.f;
            float* myl = tile[w][l];
#pragma unroll 2
            for (int t = 0; t < CF + 63; ++t) {
                float nb = __shfl_up(cur, 1);                    // V[i-1, j]
                if (l == 0) nb = (w == 0) ? 0.f : botprev[min(t + 1, CF)];
                if (t >= l && t < l + CF) {
                    float dg = prev_nb, up = nb, lf = cur;
                    float s = myl[t - l];                        // sim[i-1, j-1]
                    float mx = fmaxf(dg, fmaxf(up, lf));
                    float v = s + mx + __logf(__expf(dg - mx) + __expf(up - mx) + __expf(lf - mx));
                    cur = v;
                    myl[t - l] = v;                              // overwrite slot with V
                    if (l == 63) botcur[t - 62] = v;             // publish bottom row
                }
                prev_nb = nb;
            }
            left = cur;                                          // V[i, j0+CF]
            // coalesced float4 flush: Vsto[64w+r][j0+q] = V[64w+1+r][j0+1+q]
#pragma unroll
            for (int it = 0; it < 16; ++it) {
                int idx = (it << 6) + l;
                int r = idx >> 4, q4 = idx & 15;
                float4 v = *(const float4*)&tile[w][r][q4 << 2];
                *(float4*)(Vb + (size_t)((w << 6) + r) * VS + j0 + (q4 << 2)) = v;
            }
        }
        __syncthreads();
    }
}

// ---------------- NW backward: register-carry wave-skewed pipeline ----------------
// E[i,j] = [i==li && j==lj]
//        + E[i+1,j+1]*exp(V[i,j] - V[i+1,j+1] + sim[i,j])
//        + E[i+1,j  ]*exp(V[i,j] - V[i+1,j  ] + sim[i,j-1])
//        + E[i,  j+1]*exp(V[i,j] - V[i,  j+1] + sim[i-1,j])
// Own rows (V[i,*], sim[i-1,*]) staged in LDS; neighbor rows (V[i+1,*], sim[i,*])
// obtained by __shfl_down of register carries. Lane 63 uses staged boundary rows.
// Carries (vprev, vprev2, sprev) are re-initialized from the freshly staged tile
// at every chunk start: lanes 0..62 would refresh them in pre-active steps anyway,
// but lane 63 has NO pre-active steps (its stale vprev caused the r3 blowup).
__global__ __launch_bounds__(384, 1) void nw_bwd_kernel(const float* __restrict__ sim,
                                                        const float* __restrict__ V,
                                                        const int* __restrict__ shapes,
                                                        float* __restrict__ align_) {
    int b = blockIdx.x;
    const float* sb = sim + (size_t)b * L_ * L_;
    const float* Vb = V + (size_t)b * L_ * L_;       // Vsto layout
    float* ab = align_ + (size_t)b * L_ * L_;
    int li = min(max(shapes[2 * b + 0], 0), L_);
    int lj = min(max(shapes[2 * b + 1], 0), L_);
    __shared__ float Vt[6][64][34];          // Vt[w][l][q] = V[64w+1+l, colbase+q]
    __shared__ float St[6][64][34];          // St[w][l][q] = sim[64w+l,  colbase+q]
    __shared__ float Et[6][64][32];          // E tile per chunk
    __shared__ float Vbd[6][CB + 2];         // boundary V row 64w+65
    __shared__ float Sbd[6][CB + 2];         // boundary sim row 64w+64
    __shared__ float top[2][6][CB + 1];      // [parity][wave][0..CB], idxCB = carry E[64w+1, jhi+1]
    int tid = threadIdx.x;
    int w = tid >> 6, l = tid & 63;
    int i = (w << 6) + 1 + l;                // row 1..384
    float cur = 0.0f;                        // E[i, 385] = 0 boundary
    float vprev = 0.f, vprev2 = 0.f, sprev = 0.f;    // register carries across steps
    const int nch = L_ / CB;                 // 12
    const float* VtL = Vt[w][l];
    const float* StL = St[w][l];
    for (int T = 0; T < nch + 5; ++T) {
        int c = T - (5 - w);
        if (c >= 0 && c < nch) {
            int jhi = L_ - c * CB;           // chunk columns [jhi-CB+1 .. jhi]
            int colbase = jhi - CB;          // staged cols colbase .. colbase+CB+1
            // cooperative coalesced staging of own rows
            for (int idx = l; idx < 64 * 34; idx += 64) {
                int r = idx / 34, q = idx - r * 34;
                int col = colbase + q;
                Vt[w][r][q] = (col >= 1 && col <= L_) ? Vb[(size_t)((w << 6) + r) * VS + (col - 1)] : 0.f;
                St[w][r][q] = (col < L_) ? sb[(size_t)((w << 6) + r) * L_ + col] : 0.f;
            }
            if (l < CB + 2) {                // boundary rows for lane 63
                int col = colbase + l;
                int vrow = (w << 6) + 65;
                int srow = (w << 6) + 64;
                Vbd[w][l] = (vrow <= L_ && col >= 1 && col <= L_) ? Vb[(size_t)(vrow - 1) * VS + (col - 1)] : 0.f;
                Sbd[w][l] = (srow < L_ && col < L_) ? sb[(size_t)srow * L_ + col] : 0.f;
            }
            // chunk-start carry re-init (critical for lane 63; no-op for others)
            vprev  = VtL[CB + 1];            // V[i, jhi+1]
            vprev2 = VtL[CB + 1];
            sprev  = StL[CB + 1];
            const float* topnext = top[c & 1][(w == 5) ? 5 : (w + 1)];
            float* topcur = top[c & 1][w];
            if (l == 0) topcur[CB] = cur;    // carry E[64w+1, jhi+1]
            float prev_nb = (l == 63) ? ((w == 5) ? 0.f : topnext[CB]) : 0.f;
#pragma unroll 2
            for (int t = 0; t < CB + 63; ++t) {
                int qj = CB + 63 - t - l;
                int qc = min(max(qj, 0), CB + 1);
                float vij  = VtL[qc];                    // V[i, colbase+qc]
                float sown = StL[qc];                    // sim[i-1, colbase+qc]
                float nb   = __shfl_down(cur, 1);        // E[i+1, j]
                float vsh1 = __shfl_down(vprev, 1);      // V[i+1, j]
                float vsh2 = __shfl_down(vprev2, 1);     // V[i+1, j+1]
                float ssh0 = __shfl_down(sown, 1);       // sim[i, j-1]
                float ssh1 = __shfl_down(sprev, 1);      // sim[i, j]
                if (l == 63) {
                    nb   = (w == 5) ? 0.f : topnext[max(CB - 1 - t, 0)];
                    vsh1 = Vbd[w][qc];
                    vsh2 = Vbd[w][min(qc + 1, CB + 1)];
                    ssh0 = Sbd[w][max(qc - 1, 0)];
                    ssh1 = Sbd[w][qc];
                }
                if (qj >= 1 && qj <= CB) {
                    int j = colbase + qj;
                    float eacc = (i == li && j == lj) ? 1.0f : 0.0f;
                    float td = __expf(vij - vsh2 + ssh1) * prev_nb;
                    float tu = __expf(vij - vsh1 + ssh0) * nb;
                    float tl = __expf(vij - vprev + sown) * cur;
                    if (i < L_ && j < L_) eacc += td;
                    if (i < L_)           eacc += tu;
                    if (j < L_)           eacc += tl;
                    cur = eacc;
                    Et[w][l][qj - 1] = eacc;
                    if (l == 0) topcur[qj - 1] = eacc;   // publish top row
                }
                prev_nb = nb;
                vprev2 = vprev; vprev = vij;
                sprev = sown;
            }
            // coalesced E flush: align[64w+r][colbase+cc]
            for (int idx = l; idx < 64 * 32; idx += 64) {
                int r = idx >> 5, cc = idx & 31;
                ab[(size_t)((w << 6) + r) * L_ + colbase + cc] = Et[w][r][cc];
            }
        }
        __syncthreads();
    }
}

// ---------------- consensus[j,a] = (1/B) sum_n sum_i matrices[n,a,i]*align[n,i,j] ----------------
__global__ __launch_bounds__(256) void consensus_kernel(const float* __restrict__ x,      // (B,A,L)
                                                        const float* __restrict__ align_, // (B,L,L)
                                                        float* __restrict__ cons) {       // (L,A)
    int n  = blockIdx.y;
    int j0 = blockIdx.x * 64;
    __shared__ float ms[A_][L_];    // 39.9 KB: matrices[n] staged
    for (int idx = threadIdx.x; idx < A_ * L_; idx += 256)
        ((float*)ms)[idx] = x[(size_t)n * A_ * L_ + idx];
    __syncthreads();
    int jl = threadIdx.x & 63;
    int g  = threadIdx.x >> 6;      // 0..3
    int a0 = g * 7;                 // 0,7,14,21
    int na = (a0 + 7 <= A_) ? 7 : (A_ - a0);   // 7,7,7,5
    int j  = j0 + jl;
    float acc[7] = {0.f, 0.f, 0.f, 0.f, 0.f, 0.f, 0.f};
    const float* acol = align_ + (size_t)n * L_ * L_ + j;
    for (int i = 0; i < L_; ++i) {
        float al = acol[(size_t)i * L_];
#pragma unroll
        for (int t = 0; t < 7; ++t)
            if (t < na) acc[t] = fmaf(al, ms[a0 + t][i], acc[t]);
    }
    for (int t = 0; t < na; ++t)
        atomicAdd(&cons[(size_t)j * A_ + a0 + t], acc[t] * (1.0f / B_));
}

// ---------------- out[n,i,a] = sum_j cons[j,a] * align[n,i,j] ----------------
__global__ __launch_bounds__(256) void out_kernel(const float* __restrict__ align_,
                                                  const float* __restrict__ cons,
                                                  float* __restrict__ out) {
    int n  = blockIdx.y;
    int i0 = blockIdx.x * 32;
    __shared__ float cs[L_][A_];        // 40.0 KB
    __shared__ float as_[32][L_ + 1];   // 49.3 KB (pad: break 384-stride bank alias)
    for (int idx = threadIdx.x; idx < L_ * A_; idx += 256)
        ((float*)cs)[idx] = cons[idx];
    for (int idx = threadIdx.x; idx < 32 * L_; idx += 256) {
        int r = idx / L_, c = idx % L_;
        as_[r][c] = align_[((size_t)n * L_ + i0 + r) * L_ + c];
    }
    __syncthreads();
    for (int o = threadIdx.x; o < 32 * A_; o += 256) {
        int il = o / A_, a = o % A_;
        float s = 0.f;
        for (int jj = 0; jj < L_; ++jj)
            s = fmaf(as_[il][jj], cs[jj][a], s);
        out[((size_t)n * L_ + i0 + il) * A_ + a] = s;
    }
}

extern "C" void kernel_launch(void* const* d_in, const int* in_sizes, int n_in,
                              void* d_out, int out_size, void* d_ws, size_t ws_size,
                              hipStream_t stream) {
    const float* matrices = (const float*)d_in[0];   // (B,A,L) f32
    const int*   shapes   = (const int*)d_in[1];     // (B,2) i32
    const float* conv_w   = (const float*)d_in[2];   // (D,A,K) f32
    const float* conv_b   = (const float*)d_in[3];   // (D,) f32
    float* out = (float*)d_out;                      // (B,L,A) f32

    float* ws     = (float*)d_ws;
    float* e      = ws;                                   // B*L*D   = 12,582,912
    float* sim    = e     + (size_t)B_ * L_ * D_;         // B*L*L   =  9,437,184
    float* V      = sim   + (size_t)B_ * L_ * L_;         // B*L*L (Vsto, 16B-aligned per batch)
    float* align_ = V     + (size_t)B_ * L_ * L_;         // B*L*L   =  9,437,184
    float* wt     = align_ + (size_t)B_ * L_ * L_;        // A*K*D   =    239,616
    float* cons   = wt    + (size_t)A_ * K_ * D_;         // L*A     =      9,984

    transpose_w_kernel<<<(A_ * K_ * D_ + 255) / 256, 256, 0, stream>>>(conv_w, wt);
    conv_kernel<<<dim3(L_ / 32, B_), 512, 0, stream>>>(matrices, wt, conv_b, e);
    sim_kernel<<<dim3(L_ / 32, L_ / 32, B_), 256, 0, stream>>>(e, sim);
    nw_fwd_kernel<<<B_, 384, 0, stream>>>(sim, V);
    nw_bwd_kernel<<<B_, 384, 0, stream>>>(sim, V, shapes, align_);
    hipMemsetAsync(cons, 0, (size_t)L_ * A_ * sizeof(float), stream);
    consensus_kernel<<<dim3(L_ / 64, B_), 256, 0, stream>>>(matrices, align_, cons);
    out_kernel<<<dim3(L_ / 32, B_), 256, 0, stream>>>(align_, cons, out);
}

// Round 5
// 1653.406 us; speedup vs baseline: 1.7615x; 1.7615x over previous
//
#include <hip/hip_runtime.h>
#include <hip/hip_bf16.h>
#include <math.h>

#define B_  64
#define A_  26
#define L_  384
#define D_  512
#define K_  18
#define LP1 385   // L_ + 1
#define VS  384   // Vsto row stride; Vsto[i-1][j-1] = V[i][j]

// ---------------- conv weight transpose: (D,A,K) -> (A*K, D) ----------------
__global__ void transpose_w_kernel(const float* __restrict__ w, float* __restrict__ wt) {
    int o = blockIdx.x * blockDim.x + threadIdx.x;   // o = r*D + d
    int total = A_ * K_ * D_;
    if (o >= total) return;
    int d = o % D_;
    int r = o / D_;                                   // r = a*K + k
    wt[o] = w[(size_t)d * (A_ * K_) + r];
}

// ---------------- conv1d -> e (B, L, D) ----------------
__global__ __launch_bounds__(512) void conv_kernel(const float* __restrict__ x,     // (B, A, L)
                                                   const float* __restrict__ wt,    // (A*K, D)
                                                   const float* __restrict__ bias,  // (D,)
                                                   float* __restrict__ e) {         // (B, L, D)
    const int TL = 32;
    const int XW = TL + K_ - 1;     // 49
    int l0 = blockIdx.x * TL;
    int b  = blockIdx.y;
    int d  = threadIdx.x;           // 512 threads, one per output channel
    __shared__ float xs[A_][XW];
    for (int idx = threadIdx.x; idx < A_ * XW; idx += 512) {
        int a = idx / XW, p = idx % XW;
        int g = l0 - (K_ - 1) / 2 + p;  // l0 - 8 + p
        xs[a][p] = (g >= 0 && g < L_) ? x[((size_t)b * A_ + a) * L_ + g] : 0.0f;
    }
    __syncthreads();
    float acc[TL];
#pragma unroll
    for (int l = 0; l < TL; ++l) acc[l] = 0.0f;
#pragma unroll 1
    for (int a = 0; a < A_; ++a) {
        float xr[XW];
#pragma unroll
        for (int p = 0; p < XW; ++p) xr[p] = xs[a][p];
        const float* wrow = wt + (size_t)(a * K_) * D_ + d;
#pragma unroll
        for (int k = 0; k < K_; ++k) {
            float w = wrow[(size_t)k * D_];
#pragma unroll
            for (int l = 0; l < TL; ++l)
                acc[l] = fmaf(xr[k + l], w, acc[l]);
        }
    }
    float bv = bias[d];
#pragma unroll
    for (int l = 0; l < TL; ++l)
        e[((size_t)b * L_ + (l0 + l)) * D_ + d] = acc[l] + bv;
}

// ---------------- sim[b,l,m] = dot(e[b,l,:], e[0,m,:]) ----------------
__global__ __launch_bounds__(256) void sim_kernel(const float* __restrict__ e, float* __restrict__ sim) {
    int b  = blockIdx.z;
    int m0 = blockIdx.x * 32;
    int l0 = blockIdx.y * 32;
    __shared__ float As[32][33];
    __shared__ float Bs[32][33];
    int tid = threadIdx.x;
    int tx = tid & 15, ty = tid >> 4;
    const float* ea = e + (size_t)b * L_ * D_;
    const float* e0 = e;   // batch 0
    float acc00 = 0.f, acc01 = 0.f, acc10 = 0.f, acc11 = 0.f;
    int lrow = tid >> 3;          // 0..31
    int lcol = (tid & 7) << 2;    // 0,4,..,28
    for (int kc = 0; kc < D_; kc += 32) {
        float4 av = *(const float4*)(ea + (size_t)(l0 + lrow) * D_ + kc + lcol);
        float4 bv = *(const float4*)(e0 + (size_t)(m0 + lrow) * D_ + kc + lcol);
        As[lrow][lcol + 0] = av.x; As[lrow][lcol + 1] = av.y;
        As[lrow][lcol + 2] = av.z; As[lrow][lcol + 3] = av.w;
        Bs[lrow][lcol + 0] = bv.x; Bs[lrow][lcol + 1] = bv.y;
        Bs[lrow][lcol + 2] = bv.z; Bs[lrow][lcol + 3] = bv.w;
        __syncthreads();
#pragma unroll
        for (int kk = 0; kk < 32; ++kk) {
            float a0 = As[2 * ty][kk], a1 = As[2 * ty + 1][kk];
            float b0 = Bs[2 * tx][kk], b1 = Bs[2 * tx + 1][kk];
            acc00 = fmaf(a0, b0, acc00); acc01 = fmaf(a0, b1, acc01);
            acc10 = fmaf(a1, b0, acc10); acc11 = fmaf(a1, b1, acc11);
        }
        __syncthreads();
    }
    float* sp = sim + ((size_t)b * L_ + l0) * L_ + m0;
    sp[(2 * ty + 0) * L_ + 2 * tx + 0] = acc00;
    sp[(2 * ty + 0) * L_ + 2 * tx + 1] = acc01;
    sp[(2 * ty + 1) * L_ + 2 * tx + 0] = acc10;
    sp[(2 * ty + 1) * L_ + 2 * tx + 1] = acc11;
}

// ---------------- NW forward: ONE WAVE per batch, 6 rows/lane, no barriers ----------------
// V[i,j] = sim[i-1,j-1] + smoothmax3(V[i-1,j-1], V[i-1,j], V[i,j-1])   (g=0, t=1)
// Lane l owns rows 6l+1..6l+6. At step t it computes col j = t-l+1 for all 6 rows
// (in-register chain). Cross-lane: one shfl_up of vleft[5] = V[6l, j]; the diag
// V[6l, j-1] is last step's shfl (vup_prev). Boundary V[*,0]=V[0,*]=0 falls out of
// zero-init registers. sim lives in 3 rotating LDS panels [384][32]; V overwrites
// each sim slot in place (slot (i-1,j-1) is read exactly once, by cell (i,j));
// panels flushed to Vsto / reloaded cooperatively (float4) every 32 steps.
__global__ __launch_bounds__(64, 1) void nw_fwd_kernel(const float* __restrict__ sim, float* __restrict__ V) {
    int b = blockIdx.x;
    const float* sb = sim + (size_t)b * L_ * L_;
    float* Vb = V + (size_t)b * L_ * L_;             // Vsto layout
    __shared__ float P[3][L_][32];                   // 147,456 B
    int l = threadIdx.x;
    // prologue: load sim panels 0..2
    for (int p = 0; p < 3; ++p) {
#pragma unroll 4
        for (int k = 0; k < 48; ++k) {
            int idx = (k << 6) + l;                  // 0..3071
            int row = idx >> 3, q4 = (idx & 7) << 2;
            *(float4*)&P[p][row][q4] = *(const float4*)(sb + (size_t)row * L_ + (p << 5) + q4);
        }
    }
    float vleft[6];
#pragma unroll
    for (int r = 0; r < 6; ++r) vleft[r] = 0.f;      // V[i, 0] = 0
    float vup_prev = 0.f;                            // V[6l, 0] = 0
#pragma unroll 1
    for (int t = 0; t < L_ + 63; ++t) {
        float vup = __shfl_up(vleft[5], 1);          // V[6l, j]
        if (l == 0) vup = 0.f;                       // V[0, j] = 0
        int bcol = t - l;                            // 0-ix col = j-1
        if (bcol >= 0 && bcol < L_) {
            int slot = (bcol >> 5) % 3, q = bcol & 31;
            float dgn = vup_prev, upn = vup;
#pragma unroll
            for (int r = 0; r < 6; ++r) {
                float s = P[slot][6 * l + r][q];     // sim[i-1, j-1]
                float dg = dgn, up = upn, lf = vleft[r];
                float mx = fmaxf(dg, fmaxf(up, lf));
                float v = s + mx + __logf(__expf(dg - mx) + __expf(up - mx) + __expf(lf - mx));
                dgn = vleft[r];                      // diag for row r+1 = old V[i, j-1]
                upn = v;                             // up for row r+1 = V[i, j]
                vleft[r] = v;
                P[slot][6 * l + r][q] = v;           // in-place overwrite
            }
        }
        vup_prev = vup;
        // rotation: panel pb complete at t = 32*pb + 94 (pb = 0..8)
        if (t >= 94 && t <= 350 && ((t - 94) & 31) == 0) {
            int pb = (t - 94) >> 5;                  // flush pb, load pb+3
            int slot = pb % 3, base = pb << 5, nbase = (pb + 3) << 5;
#pragma unroll 4
            for (int k = 0; k < 48; ++k) {
                int idx = (k << 6) + l;
                int row = idx >> 3, q4 = (idx & 7) << 2;
                *(float4*)(Vb + (size_t)row * VS + base + q4) = *(const float4*)&P[slot][row][q4];
            }
#pragma unroll 4
            for (int k = 0; k < 48; ++k) {
                int idx = (k << 6) + l;
                int row = idx >> 3, q4 = (idx & 7) << 2;
                *(float4*)&P[slot][row][q4] = *(const float4*)(sb + (size_t)row * L_ + nbase + q4);
            }
        }
    }
    // epilogue: flush panels 9..11
    for (int pb = 9; pb < 12; ++pb) {
        int slot = pb % 3, base = pb << 5;
#pragma unroll 4
        for (int k = 0; k < 48; ++k) {
            int idx = (k << 6) + l;
            int row = idx >> 3, q4 = (idx & 7) << 2;
            *(float4*)(Vb + (size_t)row * VS + base + q4) = *(const float4*)&P[slot][row][q4];
        }
    }
}

// ---------------- NW backward: ONE WAVE per batch, 3 passes x 2 rows/lane ----------------
// E[i,j] = [i==li && j==lj]
//        + E[i+1,j+1]*exp(V[i,j] - V[i+1,j+1] + sim0[i][j])      (if i<L && j<L)
//        + E[i+1,j  ]*exp(V[i,j] - V[i+1,j  ] + sim0[i][j-1])    (if i<L)
//        + E[i,  j+1]*exp(V[i,j] - V[i,  j+1] + sim0[i-1][j])    (if j<L)
// Pass k (k=0,1,2) handles rows r0+1..r0+128, r0 = 256-128k (bottom first). Lane l
// owns rows i1=r0+2l+1, i2=i1+1, sweeping j right-to-left (lane l+1 one col ahead).
// Neighbor-band values E[i2+1,*], V[i2+1,*] arrive via shfl_down (+prev-step carry);
// own-row V[i,j+1]/E[i,j+1] are register carries. V & sim staged in 3 rotating LDS
// panels [129][32]; E accumulates in EP panels, flushed coalesced. Boundary row
// E[r0+129,*] passes between passes through an LDS row buffer. No barriers.
__global__ __launch_bounds__(64, 1) void nw_bwd_kernel(const float* __restrict__ sim,
                                                       const float* __restrict__ V,
                                                       const int* __restrict__ shapes,
                                                       float* __restrict__ align_) {
    int b = blockIdx.x;
    const float* sb = sim + (size_t)b * L_ * L_;
    const float* Vb = V + (size_t)b * L_ * L_;       // Vsto layout
    float* ab = align_ + (size_t)b * L_ * L_;
    int li = min(max(shapes[2 * b + 0], 0), L_);
    int lj = min(max(shapes[2 * b + 1], 0), L_);
    __shared__ float VP[3][129][32];                 // V[r0+1+rr, cb+1]
    __shared__ float SP[3][129][32];                 // sim0[r0+rr][cb]
    __shared__ float EP[3][128][32];                 // E[r0+1+rr, cb+1]
    __shared__ float Eb[2][L_ + 2];                  // boundary row E[r0+129, j]
    int l = threadIdx.x;
    for (int k = l; k < 2 * (L_ + 2); k += 64) ((float*)Eb)[k] = 0.f;
#pragma unroll 1
    for (int pass = 0; pass < 3; ++pass) {
        int r0 = 256 - 128 * pass;
        const float* Ebr = Eb[pass & 1];
        float* Ebw = Eb[(pass & 1) ^ 1];
        auto load_vs = [&](int pb) {
            int slot = pb % 3, base = pb << 5;
#pragma unroll 4
            for (int k = 0; k < 17; ++k) {
                int idx = (k << 6) + l;
                if (idx < 1032) {
                    int row = idx >> 3, q4 = (idx & 7) << 2;
                    int gr = r0 + row;
                    float4 vv = {0.f, 0.f, 0.f, 0.f}, sv = {0.f, 0.f, 0.f, 0.f};
                    if (gr < L_) {
                        vv = *(const float4*)(Vb + (size_t)gr * VS + base + q4);
                        sv = *(const float4*)(sb + (size_t)gr * L_ + base + q4);
                    }
                    *(float4*)&VP[slot][row][q4] = vv;
                    *(float4*)&SP[slot][row][q4] = sv;
                }
            }
        };
        auto flush_ep = [&](int pb) {
            int slot = pb % 3, base = pb << 5;
#pragma unroll 4
            for (int k = 0; k < 16; ++k) {
                int idx = (k << 6) + l;
                int row = idx >> 3, q4 = (idx & 7) << 2;
                *(float4*)(ab + (size_t)(r0 + row) * L_ + base + q4) = *(const float4*)&EP[slot][row][q4];
            }
        };
        for (int pb = 9; pb < 12; ++pb) load_vs(pb);
        int i1 = r0 + 2 * l + 1, i2 = i1 + 1;
        int rr0 = 2 * l, rr1 = 2 * l + 1;
        float e0 = 0.f, e1 = 0.f, vp0 = 0.f, vp1 = 0.f;  // E/V[i, j+1] carries
        float enb_prev = 0.f, vnb_prev = 0.f;            // E/V[i2+1, j+1] carries
#pragma unroll 1
        for (int t = 0; t < L_ + 63; ++t) {
            float e0s = e0, e1s = e1, vp0s = vp0, vp1s = vp1;
            float enb = __shfl_down(e0, 1);              // E[i2+1, j]
            float vnb = __shfl_down(vp0, 1);             // V[i2+1, j]
            int j = 447 - t - l;                         // 1-ix col
            if (j >= 1 && j <= L_) {
                int cb0 = j - 1, cb1 = j;
                int s0 = (cb0 >> 5) % 3, q0 = cb0 & 31;
                int s1 = (cb1 >> 5) % 3, q1 = cb1 & 31;
                float enb_td, vnb_td;
                if (l == 63) {
                    enb = Ebr[j]; enb_td = Ebr[j + 1];
                    vnb = VP[s0][128][q0];
                    vnb_td = (j < L_) ? VP[s1][128][q1] : 0.f;
                } else { enb_td = enb_prev; vnb_td = vnb_prev; }
                // ---- c=1 cell (row i2) ----
                float vij1  = VP[s0][rr1][q0];
                float s_td1 = (j < L_) ? SP[s1][rr1 + 1][q1] : 0.f;  // sim0[i2][j]
                float s_tu1 = SP[s0][rr1 + 1][q0];                    // sim0[i2][j-1]
                float s_tl1 = (j < L_) ? SP[s1][rr1][q1] : 0.f;       // sim0[i2-1][j]
                float ea1 = (i2 == li && j == lj) ? 1.f : 0.f;
                float td1 = __expf(vij1 - vnb_td + s_td1) * enb_td;
                float tu1 = __expf(vij1 - vnb + s_tu1) * enb;
                float tl1 = __expf(vij1 - vp1s + s_tl1) * e1s;
                if (i2 < L_ && j < L_) ea1 += td1;
                if (i2 < L_)           ea1 += tu1;
                if (j < L_)            ea1 += tl1;
                e1 = ea1; vp1 = vij1;
                EP[s0][rr1][q0] = e1;
                // ---- c=0 cell (row i1; i1 < L_ always) ----
                float vij0  = VP[s0][rr0][q0];
                float s_td0 = s_tl1;                                  // sim0[i1][j]
                float s_tu0 = SP[s0][rr0 + 1][q0];                    // sim0[i1][j-1]
                float s_tl0 = (j < L_) ? SP[s1][rr0][q1] : 0.f;       // sim0[i1-1][j]
                float ea0 = (i1 == li && j == lj) ? 1.f : 0.f;
                float td0 = __expf(vij0 - vp1s + s_td0) * e1s;
                float tu0 = __expf(vij0 - vij1 + s_tu0) * e1;
                float tl0 = __expf(vij0 - vp0s + s_tl0) * e0s;
                if (j < L_) ea0 += td0;
                ea0 += tu0;
                if (j < L_) ea0 += tl0;
                e0 = ea0; vp0 = vij0;
                EP[s0][rr0][q0] = e0;
                if (l == 0) Ebw[j] = e0;                 // boundary for next pass
            }
            enb_prev = enb; vnb_prev = vnb;
            // rotation: flush EP panel pb+3, load V/S panel pb (pb = 8..0)
            if (t >= 95 && t <= 351 && ((t - 95) & 31) == 0) {
                int pb = 8 - ((t - 95) >> 5);
                flush_ep(pb + 3);
                load_vs(pb);
            }
        }
        for (int pb = 0; pb < 3; ++pb) flush_ep(pb);
    }
}

// ---------------- consensus[j,a] = (1/B) sum_n sum_i matrices[n,a,i]*align[n,i,j] ----------------
__global__ __launch_bounds__(256) void consensus_kernel(const float* __restrict__ x,      // (B,A,L)
                                                        const float* __restrict__ align_, // (B,L,L)
                                                        float* __restrict__ cons) {       // (L,A)
    int n  = blockIdx.y;
    int j0 = blockIdx.x * 64;
    __shared__ float ms[A_][L_];    // 39.9 KB: matrices[n] staged
    for (int idx = threadIdx.x; idx < A_ * L_; idx += 256)
        ((float*)ms)[idx] = x[(size_t)n * A_ * L_ + idx];
    __syncthreads();
    int jl = threadIdx.x & 63;
    int g  = threadIdx.x >> 6;      // 0..3
    int a0 = g * 7;                 // 0,7,14,21
    int na = (a0 + 7 <= A_) ? 7 : (A_ - a0);   // 7,7,7,5
    int j  = j0 + jl;
    float acc[7] = {0.f, 0.f, 0.f, 0.f, 0.f, 0.f, 0.f};
    const float* acol = align_ + (size_t)n * L_ * L_ + j;
    for (int i = 0; i < L_; ++i) {
        float al = acol[(size_t)i * L_];
#pragma unroll
        for (int t = 0; t < 7; ++t)
            if (t < na) acc[t] = fmaf(al, ms[a0 + t][i], acc[t]);
    }
    for (int t = 0; t < na; ++t)
        atomicAdd(&cons[(size_t)j * A_ + a0 + t], acc[t] * (1.0f / B_));
}

// ---------------- out[n,i,a] = sum_j cons[j,a] * align[n,i,j] ----------------
__global__ __launch_bounds__(256) void out_kernel(const float* __restrict__ align_,
                                                  const float* __restrict__ cons,
                                                  float* __restrict__ out) {
    int n  = blockIdx.y;
    int i0 = blockIdx.x * 32;
    __shared__ float cs[L_][A_];        // 40.0 KB
    __shared__ float as_[32][L_ + 1];   // 49.3 KB (pad: break 384-stride bank alias)
    for (int idx = threadIdx.x; idx < L_ * A_; idx += 256)
        ((float*)cs)[idx] = cons[idx];
    for (int idx = threadIdx.x; idx < 32 * L_; idx += 256) {
        int r = idx / L_, c = idx % L_;
        as_[r][c] = align_[((size_t)n * L_ + i0 + r) * L_ + c];
    }
    __syncthreads();
    for (int o = threadIdx.x; o < 32 * A_; o += 256) {
        int il = o / A_, a = o % A_;
        float s = 0.f;
        for (int jj = 0; jj < L_; ++jj)
            s = fmaf(as_[il][jj], cs[jj][a], s);
        out[((size_t)n * L_ + i0 + il) * A_ + a] = s;
    }
}

extern "C" void kernel_launch(void* const* d_in, const int* in_sizes, int n_in,
                              void* d_out, int out_size, void* d_ws, size_t ws_size,
                              hipStream_t stream) {
    const float* matrices = (const float*)d_in[0];   // (B,A,L) f32
    const int*   shapes   = (const int*)d_in[1];     // (B,2) i32
    const float* conv_w   = (const float*)d_in[2];   // (D,A,K) f32
    const float* conv_b   = (const float*)d_in[3];   // (D,) f32
    float* out = (float*)d_out;                      // (B,L,A) f32

    float* ws     = (float*)d_ws;
    float* e      = ws;                                   // B*L*D   = 12,582,912
    float* sim    = e     + (size_t)B_ * L_ * D_;         // B*L*L   =  9,437,184
    float* V      = sim   + (size_t)B_ * L_ * L_;         // B*L*L (Vsto, 16B-aligned per batch)
    float* align_ = V     + (size_t)B_ * L_ * L_;         // B*L*L   =  9,437,184
    float* wt     = align_ + (size_t)B_ * L_ * L_;        // A*K*D   =    239,616
    float* cons   = wt    + (size_t)A_ * K_ * D_;         // L*A     =      9,984

    transpose_w_kernel<<<(A_ * K_ * D_ + 255) / 256, 256, 0, stream>>>(conv_w, wt);
    conv_kernel<<<dim3(L_ / 32, B_), 512, 0, stream>>>(matrices, wt, conv_b, e);
    sim_kernel<<<dim3(L_ / 32, L_ / 32, B_), 256, 0, stream>>>(e, sim);
    nw_fwd_kernel<<<B_, 64, 0, stream>>>(sim, V);
    nw_bwd_kernel<<<B_, 64, 0, stream>>>(sim, V, shapes, align_);
    hipMemsetAsync(cons, 0, (size_t)L_ * A_ * sizeof(float), stream);
    consensus_kernel<<<dim3(L_ / 64, B_), 256, 0, stream>>>(matrices, align_, cons);
    out_kernel<<<dim3(L_ / 32, B_), 256, 0, stream>>>(align_, cons, out);
}

// Round 6
// 1590.448 us; speedup vs baseline: 1.8313x; 1.0396x over previous
//
#include <hip/hip_runtime.h>
#include <hip/hip_bf16.h>
#include <math.h>

#define B_  64
#define A_  26
#define L_  384
#define D_  512
#define K_  18
#define LP1 385   // L_ + 1
#define VS  384   // Vsto row stride; Vsto[i-1][j-1] = V[i][j]

// DPP lane shifts (gfx9-family wave shifts, VALU-speed; bound_ctrl -> 0 fill)
__device__ __forceinline__ float dpp_up1(float x) {   // lane i <- lane i-1; lane0 <- 0
    return __int_as_float(__builtin_amdgcn_update_dpp(
        0, __float_as_int(x), 0x138, 0xF, 0xF, true));  // WAVE_SHR1
}
__device__ __forceinline__ float dpp_down1(float x) { // lane i <- lane i+1; lane63 <- 0
    return __int_as_float(__builtin_amdgcn_update_dpp(
        0, __float_as_int(x), 0x130, 0xF, 0xF, true));  // WAVE_SHL1
}

// ---------------- conv weight transpose: (D,A,K) -> (A*K, D) ----------------
__global__ void transpose_w_kernel(const float* __restrict__ w, float* __restrict__ wt) {
    int o = blockIdx.x * blockDim.x + threadIdx.x;   // o = r*D + d
    int total = A_ * K_ * D_;
    if (o >= total) return;
    int d = o % D_;
    int r = o / D_;                                   // r = a*K + k
    wt[o] = w[(size_t)d * (A_ * K_) + r];
}

// ---------------- conv1d -> e (B, L, D) ----------------
__global__ __launch_bounds__(512) void conv_kernel(const float* __restrict__ x,     // (B, A, L)
                                                   const float* __restrict__ wt,    // (A*K, D)
                                                   const float* __restrict__ bias,  // (D,)
                                                   float* __restrict__ e) {         // (B, L, D)
    const int TL = 32;
    const int XW = TL + K_ - 1;     // 49
    int l0 = blockIdx.x * TL;
    int b  = blockIdx.y;
    int d  = threadIdx.x;           // 512 threads, one per output channel
    __shared__ float xs[A_][XW];
    for (int idx = threadIdx.x; idx < A_ * XW; idx += 512) {
        int a = idx / XW, p = idx % XW;
        int g = l0 - (K_ - 1) / 2 + p;  // l0 - 8 + p
        xs[a][p] = (g >= 0 && g < L_) ? x[((size_t)b * A_ + a) * L_ + g] : 0.0f;
    }
    __syncthreads();
    float acc[TL];
#pragma unroll
    for (int l = 0; l < TL; ++l) acc[l] = 0.0f;
#pragma unroll 1
    for (int a = 0; a < A_; ++a) {
        float xr[XW];
#pragma unroll
        for (int p = 0; p < XW; ++p) xr[p] = xs[a][p];
        const float* wrow = wt + (size_t)(a * K_) * D_ + d;
#pragma unroll
        for (int k = 0; k < K_; ++k) {
            float w = wrow[(size_t)k * D_];
#pragma unroll
            for (int l = 0; l < TL; ++l)
                acc[l] = fmaf(xr[k + l], w, acc[l]);
        }
    }
    float bv = bias[d];
#pragma unroll
    for (int l = 0; l < TL; ++l)
        e[((size_t)b * L_ + (l0 + l)) * D_ + d] = acc[l] + bv;
}

// ---------------- sim[b,l,m] = dot(e[b,l,:], e[0,m,:]) ----------------
__global__ __launch_bounds__(256) void sim_kernel(const float* __restrict__ e, float* __restrict__ sim) {
    int b  = blockIdx.z;
    int m0 = blockIdx.x * 32;
    int l0 = blockIdx.y * 32;
    __shared__ float As[32][33];
    __shared__ float Bs[32][33];
    int tid = threadIdx.x;
    int tx = tid & 15, ty = tid >> 4;
    const float* ea = e + (size_t)b * L_ * D_;
    const float* e0 = e;   // batch 0
    float acc00 = 0.f, acc01 = 0.f, acc10 = 0.f, acc11 = 0.f;
    int lrow = tid >> 3;          // 0..31
    int lcol = (tid & 7) << 2;    // 0,4,..,28
    for (int kc = 0; kc < D_; kc += 32) {
        float4 av = *(const float4*)(ea + (size_t)(l0 + lrow) * D_ + kc + lcol);
        float4 bv = *(const float4*)(e0 + (size_t)(m0 + lrow) * D_ + kc + lcol);
        As[lrow][lcol + 0] = av.x; As[lrow][lcol + 1] = av.y;
        As[lrow][lcol + 2] = av.z; As[lrow][lcol + 3] = av.w;
        Bs[lrow][lcol + 0] = bv.x; Bs[lrow][lcol + 1] = bv.y;
        Bs[lrow][lcol + 2] = bv.z; Bs[lrow][lcol + 3] = bv.w;
        __syncthreads();
#pragma unroll
        for (int kk = 0; kk < 32; ++kk) {
            float a0 = As[2 * ty][kk], a1 = As[2 * ty + 1][kk];
            float b0 = Bs[2 * tx][kk], b1 = Bs[2 * tx + 1][kk];
            acc00 = fmaf(a0, b0, acc00); acc01 = fmaf(a0, b1, acc01);
            acc10 = fmaf(a1, b0, acc10); acc11 = fmaf(a1, b1, acc11);
        }
        __syncthreads();
    }
    float* sp = sim + ((size_t)b * L_ + l0) * L_ + m0;
    sp[(2 * ty + 0) * L_ + 2 * tx + 0] = acc00;
    sp[(2 * ty + 0) * L_ + 2 * tx + 1] = acc01;
    sp[(2 * ty + 1) * L_ + 2 * tx + 0] = acc10;
    sp[(2 * ty + 1) * L_ + 2 * tx + 1] = acc11;
}

// ---------------- NW forward: one wave/batch, 6 rows/lane, transposed swizzled panels, DPP ----------------
// V[i,j] = sim[i-1,j-1] + smoothmax3(V[i-1,j-1], V[i-1,j], V[i,j-1])   (g=0, t=1)
// Panels P[slot][col][row ^ col]: per-step column reads hit 16 banks (4-way, ~free);
// staging/flush float4 on the global side. V overwrites sim slots in place.
__global__ __launch_bounds__(64, 1) void nw_fwd_kernel(const float* __restrict__ sim, float* __restrict__ V) {
    int b = blockIdx.x;
    const float* sb = sim + (size_t)b * L_ * L_;
    float* Vb = V + (size_t)b * L_ * L_;             // Vsto layout
    __shared__ float P[3][32][L_];                   // 147,456 B, transposed + XOR swizzle
    int l = threadIdx.x;
    auto stage = [&](int pb) {
        int slot = pb % 3;
        const float* src = sb + (pb << 5);
#pragma unroll 4
        for (int k = 0; k < 48; ++k) {
            int idx = (k << 6) + l;
            int row = idx >> 3, q4 = (idx & 7) << 2;
            float4 v = *(const float4*)(src + (size_t)row * L_ + q4);
            P[slot][q4 + 0][row ^ (q4 + 0)] = v.x;
            P[slot][q4 + 1][row ^ (q4 + 1)] = v.y;
            P[slot][q4 + 2][row ^ (q4 + 2)] = v.z;
            P[slot][q4 + 3][row ^ (q4 + 3)] = v.w;
        }
    };
    auto flushV = [&](int pb) {
        int slot = pb % 3;
        float* dst = Vb + (pb << 5);
#pragma unroll 4
        for (int k = 0; k < 48; ++k) {
            int idx = (k << 6) + l;
            int row = idx >> 3, q4 = (idx & 7) << 2;
            float4 v;
            v.x = P[slot][q4 + 0][row ^ (q4 + 0)];
            v.y = P[slot][q4 + 1][row ^ (q4 + 1)];
            v.z = P[slot][q4 + 2][row ^ (q4 + 2)];
            v.w = P[slot][q4 + 3][row ^ (q4 + 3)];
            *(float4*)(dst + (size_t)row * VS + q4) = v;
        }
    };
    stage(0); stage(1); stage(2);
    float vleft[6], vup_prev = 0.f;
#pragma unroll
    for (int r = 0; r < 6; ++r) vleft[r] = 0.f;      // V[i,0] = 0
#pragma unroll 2
    for (int t = 0; t < L_ + 63; ++t) {
        float vup = dpp_up1(vleft[5]);               // V[6l, j]; lane0 -> 0 = V[0,j]
        int c = t - l;                               // 0-idx col = j-1
        if (c >= 0 && c < L_) {
            int slot = (c >> 5) % 3, q = c & 31;
            float* Pq = &P[slot][q][0];
            float dgn = vup_prev, upn = vup;
#pragma unroll
            for (int r = 0; r < 6; ++r) {
                int rw = (6 * l + r) ^ q;
                float s = Pq[rw];                    // sim[i-1, j-1]
                float dg = dgn, up = upn, lf = vleft[r];
                float mx = fmaxf(dg, fmaxf(up, lf));
                float v = s + mx + __logf(__expf(dg - mx) + __expf(up - mx) + __expf(lf - mx));
                dgn = vleft[r]; upn = v;
                vleft[r] = v;
                Pq[rw] = v;                          // in-place overwrite with V
            }
        }
        vup_prev = vup;
        if (t >= 94 && t <= 350 && ((t - 94) & 31) == 0) {
            int pb = (t - 94) >> 5;                  // flush pb, load pb+3
            flushV(pb);
            stage(pb + 3);
        }
    }
    for (int pb = 9; pb < 12; ++pb) flushV(pb);
}

// ---------------- NW backward: one wave/batch, 3 passes x 2 rows/lane, U-carries + DPP ----------------
// E[i,j] = [i==li && j==lj] + E[i+1,j+1]*exp(V[i,j]-U[i+1,j+1]) + E[i+1,j]*exp(V[i,j]-U[i+1,j])
//        + E[i,j+1]*exp(V[i,j]-U[i,j+1]),  U[i,j] = V[i,j] - sim0[i-1][j-1]  (computed as VP-SP).
// Neighbor U/E values arrive via DPP of register carries (lane l+1 is one column ahead);
// lane 63 uses the staged boundary row 128. All exps depend only on panel reads -> off the chain.
__global__ __launch_bounds__(64, 1) void nw_bwd_kernel(const float* __restrict__ sim,
                                                       const float* __restrict__ V,
                                                       const int* __restrict__ shapes,
                                                       float* __restrict__ align_) {
    int b = blockIdx.x;
    const float* sb = sim + (size_t)b * L_ * L_;
    const float* Vb = V + (size_t)b * L_ * L_;       // Vsto layout
    float* ab = align_ + (size_t)b * L_ * L_;
    int li = min(max(shapes[2 * b + 0], 0), L_);
    int lj = min(max(shapes[2 * b + 1], 0), L_);
    __shared__ float VP[3][32][132];                 // VP[slot][q][row] = Vsto[r0+row][base+q]
    __shared__ float SP[3][32][132];                 // SP[slot][q][row] = sb[r0+row][base+q]
    __shared__ float EP[3][32][132];                 // EP[slot][q][row] = E[r0+row+1, base+q+1]
    __shared__ float Eb[2][L_ + 2];                  // boundary row E[r0+129, j]
    int l = threadIdx.x;
    for (int k = l; k < 2 * (L_ + 2); k += 64) ((float*)Eb)[k] = 0.f;
    auto load_vs = [&](int r0, int pb) {
        int slot = pb % 3, base = pb << 5;
#pragma unroll 4
        for (int k = 0; k < 17; ++k) {
            int idx = (k << 6) + l;
            if (idx < 1032) {                        // 129 rows x 8 float4
                int row = idx >> 3, q4 = (idx & 7) << 2;
                int gr = r0 + row;
                float4 vv = {0.f, 0.f, 0.f, 0.f}, sv = {0.f, 0.f, 0.f, 0.f};
                if (gr < L_) {
                    vv = *(const float4*)(Vb + (size_t)gr * VS + base + q4);
                    sv = *(const float4*)(sb + (size_t)gr * L_ + base + q4);
                }
                VP[slot][q4 + 0][row] = vv.x; VP[slot][q4 + 1][row] = vv.y;
                VP[slot][q4 + 2][row] = vv.z; VP[slot][q4 + 3][row] = vv.w;
                SP[slot][q4 + 0][row] = sv.x; SP[slot][q4 + 1][row] = sv.y;
                SP[slot][q4 + 2][row] = sv.z; SP[slot][q4 + 3][row] = sv.w;
            }
        }
    };
    auto flush_ep = [&](int r0, int pb) {
        int slot = pb % 3, base = pb << 5;
#pragma unroll 4
        for (int k = 0; k < 16; ++k) {
            int idx = (k << 6) + l;
            int row = idx >> 3, q4 = (idx & 7) << 2;
            float4 v;
            v.x = EP[slot][q4 + 0][row]; v.y = EP[slot][q4 + 1][row];
            v.z = EP[slot][q4 + 2][row]; v.w = EP[slot][q4 + 3][row];
            *(float4*)(ab + (size_t)(r0 + row) * L_ + base + q4) = v;
        }
    };
#pragma unroll 1
    for (int pass = 0; pass < 3; ++pass) {
        int r0 = 256 - 128 * pass;
        const float* Ebr = Eb[pass & 1];
        float* Ebw = Eb[(pass & 1) ^ 1];
        load_vs(r0, 9); load_vs(r0, 10); load_vs(r0, 11);
        int i1 = r0 + 2 * l + 1, i2 = i1 + 1;
        int rr0 = 2 * l, rr1 = 2 * l + 1;
        float e0 = 0.f, e1 = 0.f;
        float u0p = 0.f, u0p2 = 0.f, u1p = 0.f, ub63p = 0.f, enb_p = 0.f;
#pragma unroll 2
        for (int t = 0; t < L_ + 63; ++t) {
            float enb   = dpp_down1(e0);             // E[i2+1, j]
            float unb   = dpp_down1(u0p);            // U[i2+1, j]
            float unbtd = dpp_down1(u0p2);           // U[i2+1, j+1]
            int j = 447 - t - l;                     // 1-idx col
            int jc = min(max(j, 1), L_);
            int cb = jc - 1;
            int slot = (cb >> 5) % 3, q = cb & 31;
            float V0 = VP[slot][q][rr0];             // V[i1, jc]
            float S0 = SP[slot][q][rr0];
            float V1 = VP[slot][q][rr1];             // V[i2, jc]
            float S1 = SP[slot][q][rr1];
            float u0 = V0 - S0, u1 = V1 - S1;        // U[i1/i2, jc]
            float enbtd;
            if (l == 63) {
                enb = Ebr[jc];
                enbtd = Ebr[jc + 1];
                unb = VP[slot][q][128] - SP[slot][q][128];   // U[r0+129, jc]
                unbtd = ub63p;
            } else {
                enbtd = enb_p;
            }
            float e0s = e0, e1s = e1;
            // weights: off the serial chain (panel reads + carries only)
            float wtd1 = __expf(V1 - unbtd);
            float wtu1 = __expf(V1 - unb);
            float wtl1 = __expf(V1 - u1p);
            float wtd0 = __expf(V0 - u1p);
            float wtu0 = __expf(V0 - u1);
            float wtl0 = __expf(V0 - u0p);
            if (j >= 1 && j <= L_) {
                float ea1 = (i2 == li && j == lj) ? 1.f : 0.f;
                if (i2 < L_ && j < L_) ea1 += wtd1 * enbtd;
                if (i2 < L_)           ea1 += wtu1 * enb;
                if (j < L_)            ea1 += wtl1 * e1s;
                float ea0 = (i1 == li && j == lj) ? 1.f : 0.f;
                if (j < L_) ea0 += wtd0 * e1s;
                ea0 += wtu0 * ea1;                   // i1 <= 383 < L_ always
                if (j < L_) ea0 += wtl0 * e0s;
                e1 = ea1; e0 = ea0;
                EP[slot][q][rr1] = ea1;
                EP[slot][q][rr0] = ea0;
                if (l == 0) Ebw[j] = ea0;            // boundary for next pass
            }
            enb_p = enb;
            u0p2 = u0p; u0p = u0; u1p = u1; ub63p = unb;
            if (t >= 95 && t <= 351 && ((t - 95) & 31) == 0) {
                int pb = 8 - ((t - 95) >> 5);
                flush_ep(r0, pb + 3);
                load_vs(r0, pb);
            }
        }
        flush_ep(r0, 2); flush_ep(r0, 1); flush_ep(r0, 0);
    }
}

// ---------------- consensus[j,a] = (1/B) sum_n sum_i matrices[n,a,i]*align[n,i,j] ----------------
__global__ __launch_bounds__(256) void consensus_kernel(const float* __restrict__ x,      // (B,A,L)
                                                        const float* __restrict__ align_, // (B,L,L)
                                                        float* __restrict__ cons) {       // (L,A)
    int n  = blockIdx.y;
    int j0 = blockIdx.x * 64;
    __shared__ float ms[A_][L_];    // 39.9 KB: matrices[n] staged
    for (int idx = threadIdx.x; idx < A_ * L_; idx += 256)
        ((float*)ms)[idx] = x[(size_t)n * A_ * L_ + idx];
    __syncthreads();
    int jl = threadIdx.x & 63;
    int g  = threadIdx.x >> 6;      // 0..3
    int a0 = g * 7;                 // 0,7,14,21
    int na = (a0 + 7 <= A_) ? 7 : (A_ - a0);   // 7,7,7,5
    int j  = j0 + jl;
    float acc[7] = {0.f, 0.f, 0.f, 0.f, 0.f, 0.f, 0.f};
    const float* acol = align_ + (size_t)n * L_ * L_ + j;
    for (int i = 0; i < L_; ++i) {
        float al = acol[(size_t)i * L_];
#pragma unroll
        for (int t = 0; t < 7; ++t)
            if (t < na) acc[t] = fmaf(al, ms[a0 + t][i], acc[t]);
    }
    for (int t = 0; t < na; ++t)
        atomicAdd(&cons[(size_t)j * A_ + a0 + t], acc[t] * (1.0f / B_));
}

// ---------------- out[n,i,a] = sum_j cons[j,a] * align[n,i,j] ----------------
__global__ __launch_bounds__(256) void out_kernel(const float* __restrict__ align_,
                                                  const float* __restrict__ cons,
                                                  float* __restrict__ out) {
    int n  = blockIdx.y;
    int i0 = blockIdx.x * 32;
    __shared__ float cs[L_][A_];        // 40.0 KB
    __shared__ float as_[32][L_ + 1];   // 49.3 KB (pad: break 384-stride bank alias)
    for (int idx = threadIdx.x; idx < L_ * A_; idx += 256)
        ((float*)cs)[idx] = cons[idx];
    for (int idx = threadIdx.x; idx < 32 * L_; idx += 256) {
        int r = idx / L_, c = idx % L_;
        as_[r][c] = align_[((size_t)n * L_ + i0 + r) * L_ + c];
    }
    __syncthreads();
    for (int o = threadIdx.x; o < 32 * A_; o += 256) {
        int il = o / A_, a = o % A_;
        float s = 0.f;
        for (int jj = 0; jj < L_; ++jj)
            s = fmaf(as_[il][jj], cs[jj][a], s);
        out[((size_t)n * L_ + i0 + il) * A_ + a] = s;
    }
}

extern "C" void kernel_launch(void* const* d_in, const int* in_sizes, int n_in,
                              void* d_out, int out_size, void* d_ws, size_t ws_size,
                              hipStream_t stream) {
    const float* matrices = (const float*)d_in[0];   // (B,A,L) f32
    const int*   shapes   = (const int*)d_in[1];     // (B,2) i32
    const float* conv_w   = (const float*)d_in[2];   // (D,A,K) f32
    const float* conv_b   = (const float*)d_in[3];   // (D,) f32
    float* out = (float*)d_out;                      // (B,L,A) f32

    float* ws     = (float*)d_ws;
    float* e      = ws;                                   // B*L*D   = 12,582,912
    float* sim    = e     + (size_t)B_ * L_ * D_;         // B*L*L   =  9,437,184
    float* V      = sim   + (size_t)B_ * L_ * L_;         // B*L*L (Vsto, 16B-aligned per batch)
    float* align_ = V     + (size_t)B_ * L_ * L_;         // B*L*L   =  9,437,184
    float* wt     = align_ + (size_t)B_ * L_ * L_;        // A*K*D   =    239,616
    float* cons   = wt    + (size_t)A_ * K_ * D_;         // L*A     =      9,984

    transpose_w_kernel<<<(A_ * K_ * D_ + 255) / 256, 256, 0, stream>>>(conv_w, wt);
    conv_kernel<<<dim3(L_ / 32, B_), 512, 0, stream>>>(matrices, wt, conv_b, e);
    sim_kernel<<<dim3(L_ / 32, L_ / 32, B_), 256, 0, stream>>>(e, sim);
    nw_fwd_kernel<<<B_, 64, 0, stream>>>(sim, V);
    nw_bwd_kernel<<<B_, 64, 0, stream>>>(sim, V, shapes, align_);
    hipMemsetAsync(cons, 0, (size_t)L_ * A_ * sizeof(float), stream);
    consensus_kernel<<<dim3(L_ / 64, B_), 256, 0, stream>>>(matrices, align_, cons);
    out_kernel<<<dim3(L_ / 32, B_), 256, 0, stream>>>(align_, cons, out);
}

// Round 7
// 1231.652 us; speedup vs baseline: 2.3647x; 1.2913x over previous
//
#include <hip/hip_runtime.h>
#include <hip/hip_bf16.h>
#include <math.h>

#define B_  64
#define A_  26
#define L_  384
#define D_  512
#define K_  18
#define LP1 385   // L_ + 1
#define VS  384   // Vsto row stride; Vsto[i-1][j-1] = V[i][j]

// DPP lane shifts (gfx9-family wave shifts, VALU-speed; bound_ctrl -> 0 fill)
__device__ __forceinline__ float dpp_up1(float x) {   // lane i <- lane i-1; lane0 <- 0
    return __int_as_float(__builtin_amdgcn_update_dpp(
        0, __float_as_int(x), 0x138, 0xF, 0xF, true));  // WAVE_SHR1
}
__device__ __forceinline__ float dpp_down1(float x) { // lane i <- lane i+1; lane63 <- 0
    return __int_as_float(__builtin_amdgcn_update_dpp(
        0, __float_as_int(x), 0x130, 0xF, 0xF, true));  // WAVE_SHL1
}

// ---------------- conv weight transpose: (D,A,K) -> (A*K, D) ----------------
__global__ void transpose_w_kernel(const float* __restrict__ w, float* __restrict__ wt) {
    int o = blockIdx.x * blockDim.x + threadIdx.x;   // o = r*D + d
    int total = A_ * K_ * D_;
    if (o >= total) return;
    int d = o % D_;
    int r = o / D_;                                   // r = a*K + k
    wt[o] = w[(size_t)d * (A_ * K_) + r];
}

// ---------------- conv1d -> e (B, L, D) ----------------
__global__ __launch_bounds__(512) void conv_kernel(const float* __restrict__ x,     // (B, A, L)
                                                   const float* __restrict__ wt,    // (A*K, D)
                                                   const float* __restrict__ bias,  // (D,)
                                                   float* __restrict__ e) {         // (B, L, D)
    const int TL = 32;
    const int XW = TL + K_ - 1;     // 49
    int l0 = blockIdx.x * TL;
    int b  = blockIdx.y;
    int d  = threadIdx.x;           // 512 threads, one per output channel
    __shared__ float xs[A_][XW];
    for (int idx = threadIdx.x; idx < A_ * XW; idx += 512) {
        int a = idx / XW, p = idx % XW;
        int g = l0 - (K_ - 1) / 2 + p;  // l0 - 8 + p
        xs[a][p] = (g >= 0 && g < L_) ? x[((size_t)b * A_ + a) * L_ + g] : 0.0f;
    }
    __syncthreads();
    float acc[TL];
#pragma unroll
    for (int l = 0; l < TL; ++l) acc[l] = 0.0f;
#pragma unroll 1
    for (int a = 0; a < A_; ++a) {
        float xr[XW];
#pragma unroll
        for (int p = 0; p < XW; ++p) xr[p] = xs[a][p];
        const float* wrow = wt + (size_t)(a * K_) * D_ + d;
#pragma unroll
        for (int k = 0; k < K_; ++k) {
            float w = wrow[(size_t)k * D_];
#pragma unroll
            for (int l = 0; l < TL; ++l)
                acc[l] = fmaf(xr[k + l], w, acc[l]);
        }
    }
    float bv = bias[d];
#pragma unroll
    for (int l = 0; l < TL; ++l)
        e[((size_t)b * L_ + (l0 + l)) * D_ + d] = acc[l] + bv;
}

// ---------------- sim[b,l,m] = dot(e[b,l,:], e[0,m,:]) ----------------
__global__ __launch_bounds__(256) void sim_kernel(const float* __restrict__ e, float* __restrict__ sim) {
    int b  = blockIdx.z;
    int m0 = blockIdx.x * 32;
    int l0 = blockIdx.y * 32;
    __shared__ float As[32][33];
    __shared__ float Bs[32][33];
    int tid = threadIdx.x;
    int tx = tid & 15, ty = tid >> 4;
    const float* ea = e + (size_t)b * L_ * D_;
    const float* e0 = e;   // batch 0
    float acc00 = 0.f, acc01 = 0.f, acc10 = 0.f, acc11 = 0.f;
    int lrow = tid >> 3;          // 0..31
    int lcol = (tid & 7) << 2;    // 0,4,..,28
    for (int kc = 0; kc < D_; kc += 32) {
        float4 av = *(const float4*)(ea + (size_t)(l0 + lrow) * D_ + kc + lcol);
        float4 bv = *(const float4*)(e0 + (size_t)(m0 + lrow) * D_ + kc + lcol);
        As[lrow][lcol + 0] = av.x; As[lrow][lcol + 1] = av.y;
        As[lrow][lcol + 2] = av.z; As[lrow][lcol + 3] = av.w;
        Bs[lrow][lcol + 0] = bv.x; Bs[lrow][lcol + 1] = bv.y;
        Bs[lrow][lcol + 2] = bv.z; Bs[lrow][lcol + 3] = bv.w;
        __syncthreads();
#pragma unroll
        for (int kk = 0; kk < 32; ++kk) {
            float a0 = As[2 * ty][kk], a1 = As[2 * ty + 1][kk];
            float b0 = Bs[2 * tx][kk], b1 = Bs[2 * tx + 1][kk];
            acc00 = fmaf(a0, b0, acc00); acc01 = fmaf(a0, b1, acc01);
            acc10 = fmaf(a1, b0, acc10); acc11 = fmaf(a1, b1, acc11);
        }
        __syncthreads();
    }
    float* sp = sim + ((size_t)b * L_ + l0) * L_ + m0;
    sp[(2 * ty + 0) * L_ + 2 * tx + 0] = acc00;
    sp[(2 * ty + 0) * L_ + 2 * tx + 1] = acc01;
    sp[(2 * ty + 1) * L_ + 2 * tx + 0] = acc10;
    sp[(2 * ty + 1) * L_ + 2 * tx + 1] = acc11;
}

// ---------------- NW forward: one wave/batch, 6 rows/lane, 4-col register tiles ----------------
// V[i,j] = sim[i-1,j-1] + smoothmax3(V[i-1,j-1], V[i-1,j], V[i,j-1])   (g=0, t=1)
// Lane l owns rows 6l+1..6l+6. Tile T covers 0-idx cols c0=4(T-l)..c0+3 (lane skew
// = 1 tile). Inputs: own sim quads (global dwordx4, prefetched 1 tile ahead);
// cross-lane: 5 DPPs/tile of lane l-1's carried row-5 V quad (bcarry) + bprev.
// No LDS. Boundary V[0,*]=V[*,0]=0 falls out of zero-init + dpp bound_ctrl.
__global__ __launch_bounds__(64, 1) void nw_fwd_kernel(const float* __restrict__ sim, float* __restrict__ V) {
    int b = blockIdx.x;
    int l = threadIdx.x;
    const float* sb = sim + (size_t)b * L_ * L_;
    float* Vb = V + (size_t)b * L_ * L_;             // Vsto layout
    const float* srow[6];
    float* vrow[6];
#pragma unroll
    for (int r = 0; r < 6; ++r) {
        srow[r] = sb + (size_t)(6 * l + r) * L_;
        vrow[r] = Vb + (size_t)(6 * l + r) * VS;
    }
    float vleft[6] = {0.f, 0.f, 0.f, 0.f, 0.f, 0.f};  // V[i, 0] = 0
    float bcarry[4] = {0.f, 0.f, 0.f, 0.f};           // row-5 V at this tile's cols
    float bprev = 0.f;                                // row-5 V at col c0-1
    float4 snxt[6];
    {
        int c0n = min(max(4 * (0 - l), 0), 380);
#pragma unroll
        for (int r = 0; r < 6; ++r) snxt[r] = *(const float4*)(srow[r] + c0n);
    }
#pragma unroll 1
    for (int T = 0; T < 159; ++T) {
        float sc[6][4];
#pragma unroll
        for (int r = 0; r < 6; ++r) {
            float4 t = snxt[r];
            sc[r][0] = t.x; sc[r][1] = t.y; sc[r][2] = t.z; sc[r][3] = t.w;
        }
        int c0n = min(max(4 * (T + 1 - l), 0), 380);
#pragma unroll
        for (int r = 0; r < 6; ++r) snxt[r] = *(const float4*)(srow[r] + c0n);
        // cross-lane inputs (whole-wave, outside divergent region)
        float d0 = dpp_up1(bprev);                   // V[6l, c0]
        float uin[4];
#pragma unroll
        for (int q = 0; q < 4; ++q) uin[q] = dpp_up1(bcarry[q]);   // V[6l, c0+q+1]
        int c0 = 4 * (T - l);
        if (c0 >= 0 && c0 <= 380) {
            float vout[6][4];
#pragma unroll
            for (int q = 0; q < 4; ++q) {
                float dg = (q == 0) ? d0 : uin[q - 1];
                float up = uin[q];
#pragma unroll
                for (int r = 0; r < 6; ++r) {
                    float lf = vleft[r];
                    float mx = fmaxf(dg, fmaxf(up, lf));
                    float v = sc[r][q] + mx + __logf(__expf(dg - mx) + __expf(up - mx) + __expf(lf - mx));
                    dg = lf;                          // diag for row r+1
                    up = v;                           // up for row r+1
                    vleft[r] = v;
                    vout[r][q] = v;
                }
            }
            bprev = bcarry[3];
#pragma unroll
            for (int q = 0; q < 4; ++q) bcarry[q] = vout[5][q];
#pragma unroll
            for (int r = 0; r < 6; ++r) {
                float4 t;
                t.x = vout[r][0]; t.y = vout[r][1]; t.z = vout[r][2]; t.w = vout[r][3];
                *(float4*)(vrow[r] + c0) = t;
            }
        }
    }
}

// ---------------- NW backward: one wave/batch, 3 passes x 2 rows/lane, 4-col register tiles ----------------
// E[i,j] = [i==li && j==lj] + E[i+1,j+1]*exp(V[i,j]-U[i+1,j+1]) + E[i+1,j]*exp(V[i,j]-U[i+1,j])
//        + E[i,j+1]*exp(V[i,j]-U[i,j+1]),   U[i,j] = V[i,j] - sim0[i-1][j-1].
// Pass p handles rows r0+1..r0+128 (r0 = 256-128p, bottom strip first); lane l owns
// rows i1=r0+2l+1, i2=i1+1, sweeping col tiles right-to-left, lane l+1 one tile ahead.
// Row i2+1 data arrives via DPP of lane l+1's carried E/U quads; lane 63 uses an
// LDS boundary row (E) + its own extra V/S row loads (U). Only LDS: 3 KB Eb buffer.
__global__ __launch_bounds__(64, 1) void nw_bwd_kernel(const float* __restrict__ sim,
                                                       const float* __restrict__ V,
                                                       const int* __restrict__ shapes,
                                                       float* __restrict__ align_) {
    int b = blockIdx.x;
    int l = threadIdx.x;
    const float* sb = sim + (size_t)b * L_ * L_;
    const float* Vb = V + (size_t)b * L_ * L_;       // Vsto layout
    float* ab = align_ + (size_t)b * L_ * L_;
    int li = min(max(shapes[2 * b + 0], 0), L_);
    int lj = min(max(shapes[2 * b + 1], 0), L_);
    __shared__ float Eb[2][388];                     // [parity][j-1] = E[r0+129, j]
    for (int k = l; k < 2 * 388; k += 64) ((float*)Eb)[k] = 0.f;
    bool L63 = (l == 63);
#pragma unroll 1
    for (int pass = 0; pass < 3; ++pass) {
        int r0 = 256 - 128 * pass;
        int i1 = r0 + 2 * l + 1, i2 = i1 + 1;
        const float* pV0 = Vb + (size_t)(r0 + 2 * l) * VS;       // V[i1, *]
        const float* pV1 = Vb + (size_t)(r0 + 2 * l + 1) * VS;   // V[i2, *]
        const float* pS0 = sb + (size_t)(r0 + 2 * l) * L_;       // sim0[i1-1][*]
        const float* pS1 = sb + (size_t)(r0 + 2 * l + 1) * L_;   // sim0[i2-1][*]
        int rb = min(r0 + 128, L_ - 1);
        const float* pV2 = Vb + (size_t)rb * VS;                 // V[r0+129, *] (lane63)
        const float* pS2 = sb + (size_t)rb * L_;                 // sim0[r0+128][*]
        float* pE0 = ab + (size_t)(i1 - 1) * L_;
        float* pE1 = ab + (size_t)(i2 - 1) * L_;
        const float* Ebr = Eb[pass & 1];
        float* Ebw = Eb[(pass & 1) ^ 1];
        float e0 = 0.f, e1 = 0.f, u0p = 0.f, u1p = 0.f;          // E/U[i*, j+1] carries
        float ecarry[4] = {0.f, 0.f, 0.f, 0.f};                  // E[i1, tile cols] (for lane l-1)
        float ucarry[4] = {0.f, 0.f, 0.f, 0.f};                  // U[i1, tile cols]
        float eprev_s = 0.f, uprev_s = 0.f;                      // E/U[i1, jhi+1] snapshots
        float eb_carry = 0.f, ub_carry = 0.f;                    // lane63 boundary carries
        float4 nV0, nV1, nS0, nS1, nV2, nS2;
        {
            int c0n = min(max(380 - 4 * (0 - (63 - l)), 0), 380);
            nV0 = *(const float4*)(pV0 + c0n); nV1 = *(const float4*)(pV1 + c0n);
            nS0 = *(const float4*)(pS0 + c0n); nS1 = *(const float4*)(pS1 + c0n);
            nV2 = *(const float4*)(pV2 + c0n); nS2 = *(const float4*)(pS2 + c0n);
        }
#pragma unroll 1
        for (int T = 0; T < 159; ++T) {
            float V0q[4], V1q[4], S0q[4], S1q[4], V2q[4], S2q[4];
            { float4 t = nV0; V0q[0]=t.x; V0q[1]=t.y; V0q[2]=t.z; V0q[3]=t.w; }
            { float4 t = nV1; V1q[0]=t.x; V1q[1]=t.y; V1q[2]=t.z; V1q[3]=t.w; }
            { float4 t = nS0; S0q[0]=t.x; S0q[1]=t.y; S0q[2]=t.z; S0q[3]=t.w; }
            { float4 t = nS1; S1q[0]=t.x; S1q[1]=t.y; S1q[2]=t.z; S1q[3]=t.w; }
            { float4 t = nV2; V2q[0]=t.x; V2q[1]=t.y; V2q[2]=t.z; V2q[3]=t.w; }
            { float4 t = nS2; S2q[0]=t.x; S2q[1]=t.y; S2q[2]=t.z; S2q[3]=t.w; }
            int m = T - (63 - l);
            int c0 = 380 - 4 * m;
            int c0n = min(max(c0 - 4, 0), 380);
            nV0 = *(const float4*)(pV0 + c0n); nV1 = *(const float4*)(pV1 + c0n);
            nS0 = *(const float4*)(pS0 + c0n); nS1 = *(const float4*)(pS1 + c0n);
            nV2 = *(const float4*)(pV2 + c0n); nS2 = *(const float4*)(pS2 + c0n);
            // cross-lane (whole-wave): lane l+1 covered these cols at T-1
            float enbtd3 = dpp_down1(eprev_s);       // E[i2+1, jhi+1]
            float unbtd3 = dpp_down1(uprev_s);       // U[i2+1, jhi+1]
            float enbc[4], unbc[4];
#pragma unroll
            for (int q = 0; q < 4; ++q) {
                enbc[q] = dpp_down1(ecarry[q]);      // E[i2+1, c0+1+q]
                unbc[q] = dpp_down1(ucarry[q]);      // U[i2+1, c0+1+q]
            }
            eprev_s = e0; uprev_s = u0p;             // snapshot AFTER dpps
            if (c0 >= 0 && c0 <= 380) {
                float ebq[4] = {0.f, 0.f, 0.f, 0.f};
                if (L63) {
                    float4 t = *(const float4*)&Ebr[c0];
                    ebq[0] = t.x; ebq[1] = t.y; ebq[2] = t.z; ebq[3] = t.w;
                }
                float u63q[4], u0c[4], u1c[4];
#pragma unroll
                for (int q = 0; q < 4; ++q) {
                    u63q[q] = V2q[q] - S2q[q];
                    u0c[q]  = V0q[q] - S0q[q];       // U[i1, c0+1+q]
                    u1c[q]  = V1q[q] - S1q[q];       // U[i2, c0+1+q]
                }
                float Eo0[4], Eo1[4];
#pragma unroll
                for (int qq = 0; qq < 4; ++qq) {
                    const int q = 3 - qq;            // descending cols
                    int j = c0 + 1 + q;
                    float enb   = L63 ? ebq[q]  : enbc[q];
                    float unb   = L63 ? u63q[q] : unbc[q];
                    float enbtd = (q == 3) ? (L63 ? eb_carry : enbtd3)
                                           : (L63 ? ebq[q + 1] : enbc[q + 1]);
                    float unbtd = (q == 3) ? (L63 ? ub_carry : unbtd3)
                                           : (L63 ? u63q[q + 1] : unbc[q + 1]);
                    bool jlt = (j < L_), i2lt = (i2 < L_);
                    float wtd1 = (i2lt && jlt) ? __expf(V1q[q] - unbtd) : 0.f;
                    float wtu1 = i2lt ? __expf(V1q[q] - unb) : 0.f;
                    float wtl1 = jlt ? __expf(V1q[q] - u1p) : 0.f;
                    float wtd0 = jlt ? __expf(V0q[q] - u1p) : 0.f;
                    float wtu0 = __expf(V0q[q] - u1c[q]);
                    float wtl0 = jlt ? __expf(V0q[q] - u0p) : 0.f;
                    float ea1 = (i2 == li && j == lj) ? 1.f : 0.f;
                    ea1 += wtd1 * enbtd + wtu1 * enb + wtl1 * e1;
                    float ea0 = (i1 == li && j == lj) ? 1.f : 0.f;
                    ea0 += wtd0 * e1 + wtu0 * ea1 + wtl0 * e0;
                    e1 = ea1; e0 = ea0;
                    u1p = u1c[q]; u0p = u0c[q];
                    Eo1[q] = ea1; Eo0[q] = ea0;
                }
                eb_carry = ebq[0]; ub_carry = u63q[0];
#pragma unroll
                for (int q = 0; q < 4; ++q) { ecarry[q] = Eo0[q]; ucarry[q] = u0c[q]; }
                float4 t0, t1;
                t0.x = Eo0[0]; t0.y = Eo0[1]; t0.z = Eo0[2]; t0.w = Eo0[3];
                t1.x = Eo1[0]; t1.y = Eo1[1]; t1.z = Eo1[2]; t1.w = Eo1[3];
                *(float4*)(pE0 + c0) = t0;
                *(float4*)(pE1 + c0) = t1;
                if (l == 0) *(float4*)&Ebw[c0] = t0;  // boundary row for next pass
            }
        }
    }
}

// ---------------- consensus[j,a] = (1/B) sum_n sum_i matrices[n,a,i]*align[n,i,j] ----------------
__global__ __launch_bounds__(256) void consensus_kernel(const float* __restrict__ x,      // (B,A,L)
                                                        const float* __restrict__ align_, // (B,L,L)
                                                        float* __restrict__ cons) {       // (L,A)
    int n  = blockIdx.y;
    int j0 = blockIdx.x * 64;
    __shared__ float ms[A_][L_];    // 39.9 KB: matrices[n] staged
    for (int idx = threadIdx.x; idx < A_ * L_; idx += 256)
        ((float*)ms)[idx] = x[(size_t)n * A_ * L_ + idx];
    __syncthreads();
    int jl = threadIdx.x & 63;
    int g  = threadIdx.x >> 6;      // 0..3
    int a0 = g * 7;                 // 0,7,14,21
    int na = (a0 + 7 <= A_) ? 7 : (A_ - a0);   // 7,7,7,5
    int j  = j0 + jl;
    float acc[7] = {0.f, 0.f, 0.f, 0.f, 0.f, 0.f, 0.f};
    const float* acol = align_ + (size_t)n * L_ * L_ + j;
    for (int i = 0; i < L_; ++i) {
        float al = acol[(size_t)i * L_];
#pragma unroll
        for (int t = 0; t < 7; ++t)
            if (t < na) acc[t] = fmaf(al, ms[a0 + t][i], acc[t]);
    }
    for (int t = 0; t < na; ++t)
        atomicAdd(&cons[(size_t)j * A_ + a0 + t], acc[t] * (1.0f / B_));
}

// ---------------- out[n,i,a] = sum_j cons[j,a] * align[n,i,j] ----------------
__global__ __launch_bounds__(256) void out_kernel(const float* __restrict__ align_,
                                                  const float* __restrict__ cons,
                                                  float* __restrict__ out) {
    int n  = blockIdx.y;
    int i0 = blockIdx.x * 32;
    __shared__ float cs[L_][A_];        // 40.0 KB
    __shared__ float as_[32][L_ + 1];   // 49.3 KB (pad: break 384-stride bank alias)
    for (int idx = threadIdx.x; idx < L_ * A_; idx += 256)
        ((float*)cs)[idx] = cons[idx];
    for (int idx = threadIdx.x; idx < 32 * L_; idx += 256) {
        int r = idx / L_, c = idx % L_;
        as_[r][c] = align_[((size_t)n * L_ + i0 + r) * L_ + c];
    }
    __syncthreads();
    for (int o = threadIdx.x; o < 32 * A_; o += 256) {
        int il = o / A_, a = o % A_;
        float s = 0.f;
        for (int jj = 0; jj < L_; ++jj)
            s = fmaf(as_[il][jj], cs[jj][a], s);
        out[((size_t)n * L_ + i0 + il) * A_ + a] = s;
    }
}

extern "C" void kernel_launch(void* const* d_in, const int* in_sizes, int n_in,
                              void* d_out, int out_size, void* d_ws, size_t ws_size,
                              hipStream_t stream) {
    const float* matrices = (const float*)d_in[0];   // (B,A,L) f32
    const int*   shapes   = (const int*)d_in[1];     // (B,2) i32
    const float* conv_w   = (const float*)d_in[2];   // (D,A,K) f32
    const float* conv_b   = (const float*)d_in[3];   // (D,) f32
    float* out = (float*)d_out;                      // (B,L,A) f32

    float* ws     = (float*)d_ws;
    float* e      = ws;                                   // B*L*D   = 12,582,912
    float* sim    = e     + (size_t)B_ * L_ * D_;         // B*L*L   =  9,437,184
    float* V      = sim   + (size_t)B_ * L_ * L_;         // B*L*L (Vsto, 16B-aligned per batch)
    float* align_ = V     + (size_t)B_ * L_ * L_;         // B*L*L   =  9,437,184
    float* wt     = align_ + (size_t)B_ * L_ * L_;        // A*K*D   =    239,616
    float* cons   = wt    + (size_t)A_ * K_ * D_;         // L*A     =      9,984

    transpose_w_kernel<<<(A_ * K_ * D_ + 255) / 256, 256, 0, stream>>>(conv_w, wt);
    conv_kernel<<<dim3(L_ / 32, B_), 512, 0, stream>>>(matrices, wt, conv_b, e);
    sim_kernel<<<dim3(L_ / 32, L_ / 32, B_), 256, 0, stream>>>(e, sim);
    nw_fwd_kernel<<<B_, 64, 0, stream>>>(sim, V);
    nw_bwd_kernel<<<B_, 64, 0, stream>>>(sim, V, shapes, align_);
    hipMemsetAsync(cons, 0, (size_t)L_ * A_ * sizeof(float), stream);
    consensus_kernel<<<dim3(L_ / 64, B_), 256, 0, stream>>>(matrices, align_, cons);
    out_kernel<<<dim3(L_ / 32, B_), 256, 0, stream>>>(align_, cons, out);
}

// Round 8
// 1088.972 us; speedup vs baseline: 2.6746x; 1.1310x over previous
//
#include <hip/hip_runtime.h>
#include <hip/hip_bf16.h>
#include <math.h>

#define B_  64
#define A_  26
#define L_  384
#define D_  512
#define K_  18
#define LP1 385   // L_ + 1
#define VS  384   // Vsto row stride; Vsto[i-1][j-1] = V[i][j]

typedef __attribute__((ext_vector_type(8))) short bf16x8;   // 8 bf16 = 4 VGPRs
typedef __attribute__((ext_vector_type(4))) float f32x4;
typedef unsigned short ushort_t;
typedef unsigned int uint_t;

// RNE f32 -> bf16 bits
__device__ __forceinline__ ushort_t f2bf(float v) {
    uint_t u = __float_as_uint(v);
    uint_t r = (u + 0x7FFFu + ((u >> 16) & 1u)) >> 16;
    return (ushort_t)r;
}

// DPP lane shifts (gfx9-family wave shifts, VALU-speed; bound_ctrl -> 0 fill)
__device__ __forceinline__ float dpp_up1(float x) {   // lane i <- lane i-1; lane0 <- 0
    return __int_as_float(__builtin_amdgcn_update_dpp(
        0, __float_as_int(x), 0x138, 0xF, 0xF, true));  // WAVE_SHR1
}
__device__ __forceinline__ float dpp_down1(float x) { // lane i <- lane i+1; lane63 <- 0
    return __int_as_float(__builtin_amdgcn_update_dpp(
        0, __float_as_int(x), 0x130, 0xF, 0xF, true));  // WAVE_SHL1
}

// ---------------- conv weight transpose: (D,A,K) -> (A*K, D) ----------------
__global__ void transpose_w_kernel(const float* __restrict__ w, float* __restrict__ wt) {
    int o = blockIdx.x * blockDim.x + threadIdx.x;   // o = r*D + d
    int total = A_ * K_ * D_;
    if (o >= total) return;
    int d = o % D_;
    int r = o / D_;                                   // r = a*K + k
    wt[o] = w[(size_t)d * (A_ * K_) + r];
}

// ---------------- conv1d -> e_hi/e_lo (B, L, D) bf16 split ----------------
__global__ __launch_bounds__(512) void conv_kernel(const float* __restrict__ x,     // (B, A, L)
                                                   const float* __restrict__ wt,    // (A*K, D)
                                                   const float* __restrict__ bias,  // (D,)
                                                   ushort_t* __restrict__ ehi,      // (B, L, D) bf16
                                                   ushort_t* __restrict__ elo) {    // (B, L, D) bf16
    const int TL = 32;
    const int XW = TL + K_ - 1;     // 49
    int l0 = blockIdx.x * TL;
    int b  = blockIdx.y;
    int d  = threadIdx.x;           // 512 threads, one per output channel
    __shared__ float xs[A_][XW];
    for (int idx = threadIdx.x; idx < A_ * XW; idx += 512) {
        int a = idx / XW, p = idx % XW;
        int g = l0 - (K_ - 1) / 2 + p;  // l0 - 8 + p
        xs[a][p] = (g >= 0 && g < L_) ? x[((size_t)b * A_ + a) * L_ + g] : 0.0f;
    }
    __syncthreads();
    float acc[TL];
#pragma unroll
    for (int l = 0; l < TL; ++l) acc[l] = 0.0f;
#pragma unroll 1
    for (int a = 0; a < A_; ++a) {
        float xr[XW];
#pragma unroll
        for (int p = 0; p < XW; ++p) xr[p] = xs[a][p];
        const float* wrow = wt + (size_t)(a * K_) * D_ + d;
#pragma unroll
        for (int k = 0; k < K_; ++k) {
            float w = wrow[(size_t)k * D_];
#pragma unroll
            for (int l = 0; l < TL; ++l)
                acc[l] = fmaf(xr[k + l], w, acc[l]);
        }
    }
    float bv = bias[d];
#pragma unroll
    for (int l = 0; l < TL; ++l) {
        float v = acc[l] + bv;
        ushort_t h = f2bf(v);
        float hf = __uint_as_float(((uint_t)h) << 16);
        ushort_t lo = f2bf(v - hf);
        size_t idx = ((size_t)b * L_ + (l0 + l)) * D_ + d;
        ehi[idx] = h;
        elo[idx] = lo;
    }
}

// ---------------- sim = E_b · E_0^T via split-bf16 MFMA ----------------
// sim ~= hi·hi + hi·lo + lo·hi (lo·lo dropped, ~2^-17 relative).
// mfma_f32_16x16x32_bf16 layouts (learn_hip m89-verified):
//   A-frag: row i = lane&15, k = (lane>>4)*8 + t  (8 contiguous bf16 -> 1 dwordx4)
//   B-frag: col j = lane&15, k = (lane>>4)*8 + t  (= row m0+j of e0, contiguous d)
//   C/D  : col = lane&15, row = (lane>>4)*4 + reg
// Block = 64x64 tile, 4 waves, each wave one 32x32 quadrant (2x2 fragment grid).
// No LDS: every fragment is one 16B global load, e_hi/e_lo are L2-resident.
__global__ __launch_bounds__(256) void sim_kernel(const ushort_t* __restrict__ ehi,
                                                  const ushort_t* __restrict__ elo,
                                                  float* __restrict__ sim) {
    int b = blockIdx.z;
    int w = threadIdx.x >> 6;
    int lane = threadIdx.x & 63;
    int l0 = blockIdx.y * 64 + 32 * (w >> 1);
    int m0 = blockIdx.x * 64 + 32 * (w & 1);
    int r = lane & 15, g = lane >> 4;
    size_t rowA = ((size_t)b * L_ + l0 + r) * D_ + g * 8;
    size_t rowB = ((size_t)m0 + r) * D_ + g * 8;      // batch 0
    const ushort_t* pah = ehi + rowA;
    const ushort_t* pal = elo + rowA;
    const ushort_t* pbh = ehi + rowB;
    const ushort_t* pbl = elo + rowB;
    f32x4 acc00 = {0.f, 0.f, 0.f, 0.f}, acc01 = acc00, acc10 = acc00, acc11 = acc00;
#pragma unroll 2
    for (int ks = 0; ks < 16; ++ks) {
        int off = ks * 32;
        bf16x8 Ah0 = *(const bf16x8*)(pah + off);
        bf16x8 Ah1 = *(const bf16x8*)(pah + 16 * D_ + off);
        bf16x8 Al0 = *(const bf16x8*)(pal + off);
        bf16x8 Al1 = *(const bf16x8*)(pal + 16 * D_ + off);
        bf16x8 Bh0 = *(const bf16x8*)(pbh + off);
        bf16x8 Bh1 = *(const bf16x8*)(pbh + 16 * D_ + off);
        bf16x8 Bl0 = *(const bf16x8*)(pbl + off);
        bf16x8 Bl1 = *(const bf16x8*)(pbl + 16 * D_ + off);
        acc00 = __builtin_amdgcn_mfma_f32_16x16x32_bf16(Ah0, Bh0, acc00, 0, 0, 0);
        acc00 = __builtin_amdgcn_mfma_f32_16x16x32_bf16(Ah0, Bl0, acc00, 0, 0, 0);
        acc00 = __builtin_amdgcn_mfma_f32_16x16x32_bf16(Al0, Bh0, acc00, 0, 0, 0);
        acc01 = __builtin_amdgcn_mfma_f32_16x16x32_bf16(Ah0, Bh1, acc01, 0, 0, 0);
        acc01 = __builtin_amdgcn_mfma_f32_16x16x32_bf16(Ah0, Bl1, acc01, 0, 0, 0);
        acc01 = __builtin_amdgcn_mfma_f32_16x16x32_bf16(Al0, Bh1, acc01, 0, 0, 0);
        acc10 = __builtin_amdgcn_mfma_f32_16x16x32_bf16(Ah1, Bh0, acc10, 0, 0, 0);
        acc10 = __builtin_amdgcn_mfma_f32_16x16x32_bf16(Ah1, Bl0, acc10, 0, 0, 0);
        acc10 = __builtin_amdgcn_mfma_f32_16x16x32_bf16(Al1, Bh0, acc10, 0, 0, 0);
        acc11 = __builtin_amdgcn_mfma_f32_16x16x32_bf16(Ah1, Bh1, acc11, 0, 0, 0);
        acc11 = __builtin_amdgcn_mfma_f32_16x16x32_bf16(Ah1, Bl1, acc11, 0, 0, 0);
        acc11 = __builtin_amdgcn_mfma_f32_16x16x32_bf16(Al1, Bh1, acc11, 0, 0, 0);
    }
    float* sp = sim + ((size_t)b * L_ + l0) * L_ + m0;
#pragma unroll
    for (int v = 0; v < 4; ++v) {
        int row = g * 4 + v;
        sp[(size_t)row * L_ + r]             = acc00[v];
        sp[(size_t)row * L_ + 16 + r]        = acc01[v];
        sp[(size_t)(16 + row) * L_ + r]      = acc10[v];
        sp[(size_t)(16 + row) * L_ + 16 + r] = acc11[v];
    }
}

// ---------------- NW forward: one wave/batch, 6 rows/lane, 4-col register tiles ----------------
// V[i,j] = sim[i-1,j-1] + smoothmax3(V[i-1,j-1], V[i-1,j], V[i,j-1])   (g=0, t=1)
__global__ __launch_bounds__(64, 1) void nw_fwd_kernel(const float* __restrict__ sim, float* __restrict__ V) {
    int b = blockIdx.x;
    int l = threadIdx.x;
    const float* sb = sim + (size_t)b * L_ * L_;
    float* Vb = V + (size_t)b * L_ * L_;             // Vsto layout
    const float* srow[6];
    float* vrow[6];
#pragma unroll
    for (int r = 0; r < 6; ++r) {
        srow[r] = sb + (size_t)(6 * l + r) * L_;
        vrow[r] = Vb + (size_t)(6 * l + r) * VS;
    }
    float vleft[6] = {0.f, 0.f, 0.f, 0.f, 0.f, 0.f};  // V[i, 0] = 0
    float bcarry[4] = {0.f, 0.f, 0.f, 0.f};           // row-5 V at this tile's cols
    float bprev = 0.f;                                // row-5 V at col c0-1
    float4 snxt[6];
    {
        int c0n = min(max(4 * (0 - l), 0), 380);
#pragma unroll
        for (int r = 0; r < 6; ++r) snxt[r] = *(const float4*)(srow[r] + c0n);
    }
#pragma unroll 1
    for (int T = 0; T < 159; ++T) {
        float sc[6][4];
#pragma unroll
        for (int r = 0; r < 6; ++r) {
            float4 t = snxt[r];
            sc[r][0] = t.x; sc[r][1] = t.y; sc[r][2] = t.z; sc[r][3] = t.w;
        }
        int c0n = min(max(4 * (T + 1 - l), 0), 380);
#pragma unroll
        for (int r = 0; r < 6; ++r) snxt[r] = *(const float4*)(srow[r] + c0n);
        // cross-lane inputs (whole-wave, outside divergent region)
        float d0 = dpp_up1(bprev);                   // V[6l, c0]
        float uin[4];
#pragma unroll
        for (int q = 0; q < 4; ++q) uin[q] = dpp_up1(bcarry[q]);   // V[6l, c0+q+1]
        int c0 = 4 * (T - l);
        if (c0 >= 0 && c0 <= 380) {
            float vout[6][4];
#pragma unroll
            for (int q = 0; q < 4; ++q) {
                float dg = (q == 0) ? d0 : uin[q - 1];
                float up = uin[q];
#pragma unroll
                for (int r = 0; r < 6; ++r) {
                    float lf = vleft[r];
                    float mx = fmaxf(dg, fmaxf(up, lf));
                    float v = sc[r][q] + mx + __logf(__expf(dg - mx) + __expf(up - mx) + __expf(lf - mx));
                    dg = lf;                          // diag for row r+1
                    up = v;                           // up for row r+1
                    vleft[r] = v;
                    vout[r][q] = v;
                }
            }
            bprev = bcarry[3];
#pragma unroll
            for (int q = 0; q < 4; ++q) bcarry[q] = vout[5][q];
#pragma unroll
            for (int r = 0; r < 6; ++r) {
                float4 t;
                t.x = vout[r][0]; t.y = vout[r][1]; t.z = vout[r][2]; t.w = vout[r][3];
                *(float4*)(vrow[r] + c0) = t;
            }
        }
    }
}

// ---------------- NW backward: one wave/batch, 3 passes x 2 rows/lane, 4-col register tiles ----------------
__global__ __launch_bounds__(64, 1) void nw_bwd_kernel(const float* __restrict__ sim,
                                                       const float* __restrict__ V,
                                                       const int* __restrict__ shapes,
                                                       float* __restrict__ align_) {
    int b = blockIdx.x;
    int l = threadIdx.x;
    const float* sb = sim + (size_t)b * L_ * L_;
    const float* Vb = V + (size_t)b * L_ * L_;       // Vsto layout
    float* ab = align_ + (size_t)b * L_ * L_;
    int li = min(max(shapes[2 * b + 0], 0), L_);
    int lj = min(max(shapes[2 * b + 1], 0), L_);
    __shared__ float Eb[2][388];                     // [parity][j-1] = E[r0+129, j]
    for (int k = l; k < 2 * 388; k += 64) ((float*)Eb)[k] = 0.f;
    bool L63 = (l == 63);
#pragma unroll 1
    for (int pass = 0; pass < 3; ++pass) {
        int r0 = 256 - 128 * pass;
        int i1 = r0 + 2 * l + 1, i2 = i1 + 1;
        const float* pV0 = Vb + (size_t)(r0 + 2 * l) * VS;       // V[i1, *]
        const float* pV1 = Vb + (size_t)(r0 + 2 * l + 1) * VS;   // V[i2, *]
        const float* pS0 = sb + (size_t)(r0 + 2 * l) * L_;       // sim0[i1-1][*]
        const float* pS1 = sb + (size_t)(r0 + 2 * l + 1) * L_;   // sim0[i2-1][*]
        int rb = min(r0 + 128, L_ - 1);
        const float* pV2 = Vb + (size_t)rb * VS;                 // V[r0+129, *] (lane63)
        const float* pS2 = sb + (size_t)rb * L_;                 // sim0[r0+128][*]
        float* pE0 = ab + (size_t)(i1 - 1) * L_;
        float* pE1 = ab + (size_t)(i2 - 1) * L_;
        const float* Ebr = Eb[pass & 1];
        float* Ebw = Eb[(pass & 1) ^ 1];
        float e0 = 0.f, e1 = 0.f, u0p = 0.f, u1p = 0.f;          // E/U[i*, j+1] carries
        float ecarry[4] = {0.f, 0.f, 0.f, 0.f};                  // E[i1, tile cols] (for lane l-1)
        float ucarry[4] = {0.f, 0.f, 0.f, 0.f};                  // U[i1, tile cols]
        float eprev_s = 0.f, uprev_s = 0.f;                      // E/U[i1, jhi+1] snapshots
        float eb_carry = 0.f, ub_carry = 0.f;                    // lane63 boundary carries
        float4 nV0, nV1, nS0, nS1, nV2, nS2;
        {
            int c0n = min(max(380 - 4 * (0 - (63 - l)), 0), 380);
            nV0 = *(const float4*)(pV0 + c0n); nV1 = *(const float4*)(pV1 + c0n);
            nS0 = *(const float4*)(pS0 + c0n); nS1 = *(const float4*)(pS1 + c0n);
            nV2 = *(const float4*)(pV2 + c0n); nS2 = *(const float4*)(pS2 + c0n);
        }
#pragma unroll 1
        for (int T = 0; T < 159; ++T) {
            float V0q[4], V1q[4], S0q[4], S1q[4], V2q[4], S2q[4];
            { float4 t = nV0; V0q[0]=t.x; V0q[1]=t.y; V0q[2]=t.z; V0q[3]=t.w; }
            { float4 t = nV1; V1q[0]=t.x; V1q[1]=t.y; V1q[2]=t.z; V1q[3]=t.w; }
            { float4 t = nS0; S0q[0]=t.x; S0q[1]=t.y; S0q[2]=t.z; S0q[3]=t.w; }
            { float4 t = nS1; S1q[0]=t.x; S1q[1]=t.y; S1q[2]=t.z; S1q[3]=t.w; }
            { float4 t = nV2; V2q[0]=t.x; V2q[1]=t.y; V2q[2]=t.z; V2q[3]=t.w; }
            { float4 t = nS2; S2q[0]=t.x; S2q[1]=t.y; S2q[2]=t.z; S2q[3]=t.w; }
            int m = T - (63 - l);
            int c0 = 380 - 4 * m;
            int c0n = min(max(c0 - 4, 0), 380);
            nV0 = *(const float4*)(pV0 + c0n); nV1 = *(const float4*)(pV1 + c0n);
            nS0 = *(const float4*)(pS0 + c0n); nS1 = *(const float4*)(pS1 + c0n);
            nV2 = *(const float4*)(pV2 + c0n); nS2 = *(const float4*)(pS2 + c0n);
            // cross-lane (whole-wave): lane l+1 covered these cols at T-1
            float enbtd3 = dpp_down1(eprev_s);       // E[i2+1, jhi+1]
            float unbtd3 = dpp_down1(uprev_s);       // U[i2+1, jhi+1]
            float enbc[4], unbc[4];
#pragma unroll
            for (int q = 0; q < 4; ++q) {
                enbc[q] = dpp_down1(ecarry[q]);      // E[i2+1, c0+1+q]
                unbc[q] = dpp_down1(ucarry[q]);      // U[i2+1, c0+1+q]
            }
            eprev_s = e0; uprev_s = u0p;             // snapshot AFTER dpps
            if (c0 >= 0 && c0 <= 380) {
                float ebq[4] = {0.f, 0.f, 0.f, 0.f};
                if (L63) {
                    float4 t = *(const float4*)&Ebr[c0];
                    ebq[0] = t.x; ebq[1] = t.y; ebq[2] = t.z; ebq[3] = t.w;
                }
                float u63q[4], u0c[4], u1c[4];
#pragma unroll
                for (int q = 0; q < 4; ++q) {
                    u63q[q] = V2q[q] - S2q[q];
                    u0c[q]  = V0q[q] - S0q[q];       // U[i1, c0+1+q]
                    u1c[q]  = V1q[q] - S1q[q];       // U[i2, c0+1+q]
                }
                float Eo0[4], Eo1[4];
#pragma unroll
                for (int qq = 0; qq < 4; ++qq) {
                    const int q = 3 - qq;            // descending cols
                    int j = c0 + 1 + q;
                    float enb   = L63 ? ebq[q]  : enbc[q];
                    float unb   = L63 ? u63q[q] : unbc[q];
                    float enbtd = (q == 3) ? (L63 ? eb_carry : enbtd3)
                                           : (L63 ? ebq[q + 1] : enbc[q + 1]);
                    float unbtd = (q == 3) ? (L63 ? ub_carry : unbtd3)
                                           : (L63 ? u63q[q + 1] : unbc[q + 1]);
                    bool jlt = (j < L_), i2lt = (i2 < L_);
                    float wtd1 = (i2lt && jlt) ? __expf(V1q[q] - unbtd) : 0.f;
                    float wtu1 = i2lt ? __expf(V1q[q] - unb) : 0.f;
                    float wtl1 = jlt ? __expf(V1q[q] - u1p) : 0.f;
                    float wtd0 = jlt ? __expf(V0q[q] - u1p) : 0.f;
                    float wtu0 = __expf(V0q[q] - u1c[q]);
                    float wtl0 = jlt ? __expf(V0q[q] - u0p) : 0.f;
                    float ea1 = (i2 == li && j == lj) ? 1.f : 0.f;
                    ea1 += wtd1 * enbtd + wtu1 * enb + wtl1 * e1;
                    float ea0 = (i1 == li && j == lj) ? 1.f : 0.f;
                    ea0 += wtd0 * e1 + wtu0 * ea1 + wtl0 * e0;
                    e1 = ea1; e0 = ea0;
                    u1p = u1c[q]; u0p = u0c[q];
                    Eo1[q] = ea1; Eo0[q] = ea0;
                }
                eb_carry = ebq[0]; ub_carry = u63q[0];
#pragma unroll
                for (int q = 0; q < 4; ++q) { ecarry[q] = Eo0[q]; ucarry[q] = u0c[q]; }
                float4 t0, t1;
                t0.x = Eo0[0]; t0.y = Eo0[1]; t0.z = Eo0[2]; t0.w = Eo0[3];
                t1.x = Eo1[0]; t1.y = Eo1[1]; t1.z = Eo1[2]; t1.w = Eo1[3];
                *(float4*)(pE0 + c0) = t0;
                *(float4*)(pE1 + c0) = t1;
                if (l == 0) *(float4*)&Ebw[c0] = t0;  // boundary row for next pass
            }
        }
    }
}

// ---------------- consensus[j,a] = (1/B) sum_n sum_i matrices[n,a,i]*align[n,i,j] ----------------
__global__ __launch_bounds__(256) void consensus_kernel(const float* __restrict__ x,      // (B,A,L)
                                                        const float* __restrict__ align_, // (B,L,L)
                                                        float* __restrict__ cons) {       // (L,A)
    int n  = blockIdx.y;
    int j0 = blockIdx.x * 64;
    __shared__ float ms[A_][L_];    // 39.9 KB: matrices[n] staged
    for (int idx = threadIdx.x; idx < A_ * L_; idx += 256)
        ((float*)ms)[idx] = x[(size_t)n * A_ * L_ + idx];
    __syncthreads();
    int jl = threadIdx.x & 63;
    int g  = threadIdx.x >> 6;      // 0..3
    int a0 = g * 7;                 // 0,7,14,21
    int na = (a0 + 7 <= A_) ? 7 : (A_ - a0);   // 7,7,7,5
    int j  = j0 + jl;
    float acc[7] = {0.f, 0.f, 0.f, 0.f, 0.f, 0.f, 0.f};
    const float* acol = align_ + (size_t)n * L_ * L_ + j;
    for (int i = 0; i < L_; ++i) {
        float al = acol[(size_t)i * L_];
#pragma unroll
        for (int t = 0; t < 7; ++t)
            if (t < na) acc[t] = fmaf(al, ms[a0 + t][i], acc[t]);
    }
    for (int t = 0; t < na; ++t)
        atomicAdd(&cons[(size_t)j * A_ + a0 + t], acc[t] * (1.0f / B_));
}

// ---------------- out[n,i,a] = sum_j cons[j,a] * align[n,i,j] ----------------
__global__ __launch_bounds__(256) void out_kernel(const float* __restrict__ align_,
                                                  const float* __restrict__ cons,
                                                  float* __restrict__ out) {
    int n  = blockIdx.y;
    int i0 = blockIdx.x * 32;
    __shared__ float cs[L_][A_];        // 40.0 KB
    __shared__ float as_[32][L_ + 1];   // 49.3 KB (pad: break 384-stride bank alias)
    for (int idx = threadIdx.x; idx < L_ * A_; idx += 256)
        ((float*)cs)[idx] = cons[idx];
    for (int idx = threadIdx.x; idx < 32 * L_; idx += 256) {
        int r = idx / L_, c = idx % L_;
        as_[r][c] = align_[((size_t)n * L_ + i0 + r) * L_ + c];
    }
    __syncthreads();
    for (int o = threadIdx.x; o < 32 * A_; o += 256) {
        int il = o / A_, a = o % A_;
        float s = 0.f;
        for (int jj = 0; jj < L_; ++jj)
            s = fmaf(as_[il][jj], cs[jj][a], s);
        out[((size_t)n * L_ + i0 + il) * A_ + a] = s;
    }
}

extern "C" void kernel_launch(void* const* d_in, const int* in_sizes, int n_in,
                              void* d_out, int out_size, void* d_ws, size_t ws_size,
                              hipStream_t stream) {
    const float* matrices = (const float*)d_in[0];   // (B,A,L) f32
    const int*   shapes   = (const int*)d_in[1];     // (B,2) i32
    const float* conv_w   = (const float*)d_in[2];   // (D,A,K) f32
    const float* conv_b   = (const float*)d_in[3];   // (D,) f32
    float* out = (float*)d_out;                      // (B,L,A) f32

    char* p = (char*)d_ws;
    ushort_t* ehi = (ushort_t*)p;  p += (size_t)B_ * L_ * D_ * 2;   // 25.2 MB bf16
    ushort_t* elo = (ushort_t*)p;  p += (size_t)B_ * L_ * D_ * 2;   // 25.2 MB bf16
    float* sim    = (float*)p;     p += (size_t)B_ * L_ * L_ * 4;   // 37.7 MB
    float* V      = (float*)p;     p += (size_t)B_ * L_ * L_ * 4;   // 37.7 MB (Vsto)
    float* align_ = (float*)p;     p += (size_t)B_ * L_ * L_ * 4;   // 37.7 MB
    float* wt     = (float*)p;     p += (size_t)A_ * K_ * D_ * 4;   //  1.0 MB
    float* cons   = (float*)p;                                      // 40 KB

    transpose_w_kernel<<<(A_ * K_ * D_ + 255) / 256, 256, 0, stream>>>(conv_w, wt);
    conv_kernel<<<dim3(L_ / 32, B_), 512, 0, stream>>>(matrices, wt, conv_b, ehi, elo);
    sim_kernel<<<dim3(L_ / 64, L_ / 64, B_), 256, 0, stream>>>(ehi, elo, sim);
    nw_fwd_kernel<<<B_, 64, 0, stream>>>(sim, V);
    nw_bwd_kernel<<<B_, 64, 0, stream>>>(sim, V, shapes, align_);
    hipMemsetAsync(cons, 0, (size_t)L_ * A_ * sizeof(float), stream);
    consensus_kernel<<<dim3(L_ / 64, B_), 256, 0, stream>>>(matrices, align_, cons);
    out_kernel<<<dim3(L_ / 32, B_), 256, 0, stream>>>(align_, cons, out);
}